// Round 2
// baseline (419.111 us; speedup 1.0000x reference)
//
#include <hip/hip_runtime.h>
#include <hip/hip_bf16.h>
#include <math.h>

#define DIM     1024
#define NHEADS  16
#define HD      64
#define BATCH   4
#define SEQ     2048
#define M_TOT   (BATCH * SEQ)   // 8192
#define QSCALE  0.180336880111f  // 0.125 * log2(e): softmax via exp2

using short8 = __attribute__((ext_vector_type(8))) short;   // 8 bf16 (4 VGPRs)
using f32x4  = __attribute__((ext_vector_type(4))) float;   // MFMA accumulator

__device__ inline unsigned short f2bf(float x) {
    __hip_bfloat16 h = __float2bfloat16(x);
    unsigned short u;
    __builtin_memcpy(&u, &h, sizeof(u));
    return u;
}
__device__ inline void st_o(float* p, float v)          { *p = v; }
__device__ inline void st_o(unsigned short* p, float v) { *p = f2bf(v); }

// async global->LDS, 16B per lane; lptr must be wave-uniform (lane scatters
// at lptr + lane*16 per HW rule).
__device__ inline void async16(const void* g, void* l) {
    __builtin_amdgcn_global_load_lds(
        (const __attribute__((address_space(1))) void*)g,
        (__attribute__((address_space(3))) void*)l, 16, 0, 0);
}

// ---------- fp32 -> bf16 convert, 3 tensors in one launch ----------
__global__ __launch_bounds__(256) void cvt3(
    const float* __restrict__ S0, const float* __restrict__ S1,
    const float* __restrict__ S2,
    unsigned short* __restrict__ D0, unsigned short* __restrict__ D1,
    unsigned short* __restrict__ D2)
{
    const float* src; unsigned short* dst;
    switch (blockIdx.y) {
        case 0:  src = S0; dst = D0; break;
        case 1:  src = S1; dst = D1; break;
        default: src = S2; dst = D2; break;
    }
    const size_t i = ((size_t)blockIdx.x * 256 + threadIdx.x) * 16;
    unsigned short tmp[16];
    #pragma unroll
    for (int p = 0; p < 4; ++p) {
        const float4 v = *(const float4*)(src + i + p * 4);
        tmp[p * 4 + 0] = f2bf(v.x); tmp[p * 4 + 1] = f2bf(v.y);
        tmp[p * 4 + 2] = f2bf(v.z); tmp[p * 4 + 3] = f2bf(v.w);
    }
    *(short8*)(dst + i)     = *(short8*)&tmp[0];
    *(short8*)(dst + i + 8) = *(short8*)&tmp[8];
}

// ---------- weight convert + transpose, 4 weights in one launch ----------
// Wt[n][k] = bf16(W[k][n])
__global__ __launch_bounds__(256) void wcvt4(
    const float* __restrict__ W0, const float* __restrict__ W1,
    const float* __restrict__ W2, const float* __restrict__ W3,
    unsigned short* __restrict__ T0, unsigned short* __restrict__ T1,
    unsigned short* __restrict__ T2, unsigned short* __restrict__ T3)
{
    const float* W; unsigned short* Wt;
    switch (blockIdx.z) {
        case 0:  W = W0; Wt = T0; break;
        case 1:  W = W1; Wt = T1; break;
        case 2:  W = W2; Wt = T2; break;
        default: W = W3; Wt = T3; break;
    }
    __shared__ unsigned short tile[32][33];
    const int t = threadIdx.x;
    const int tx = t & 31, ty = t >> 5;              // 32 x 8
    const int n0 = blockIdx.x * 32, k0 = blockIdx.y * 32;
    #pragma unroll
    for (int i = 0; i < 4; ++i) {
        const int kk = ty + i * 8;
        tile[kk][tx] = f2bf(W[(size_t)(k0 + kk) * DIM + n0 + tx]);
    }
    __syncthreads();
    #pragma unroll
    for (int i = 0; i < 4; ++i) {
        const int nn = ty + i * 8;
        Wt[(size_t)(n0 + nn) * DIM + k0 + tx] = tile[tx][nn];
    }
}

// ---------- V transpose: vt[(b*16+h)*64+d][s] = vf[b*S+s][h*64+d] ----------
__global__ __launch_bounds__(256) void vtrans(const unsigned short* __restrict__ vf,
                                              unsigned short* __restrict__ vt) {
    __shared__ unsigned short tile[64][72];
    const int t = threadIdx.x;
    const int b = blockIdx.z, h = blockIdx.y, s0 = blockIdx.x * 64;
    const int r = t >> 2, c = (t & 3) * 16;
    const unsigned short* src = vf + (size_t)(b * SEQ + s0 + r) * DIM + h * HD + c;
    *(short8*)&tile[r][c]     = *(const short8*)src;
    *(short8*)&tile[r][c + 8] = *(const short8*)(src + 8);
    __syncthreads();
    unsigned short tmp[16];
    #pragma unroll
    for (int j = 0; j < 16; ++j) tmp[j] = tile[c + j][r];   // r is d, c is s-off
    unsigned short* dst = vt + ((size_t)(b * NHEADS + h) * HD + r) * SEQ + s0 + c;
    *(short8*)dst       = *(short8*)&tmp[0];
    *(short8*)(dst + 8) = *(short8*)&tmp[8];
}

// ---------- MFMA GEMM (m97 structure): Y = (A @ Wt^T + bias) * scale ----------
// A: [M][1024] bf16, Wt: [N=1024][K=1024] bf16. 128x128 tile, BK=32,
// 4 waves (2x2), global_load_lds 16B staging, no LDS padding.
template <typename TY>
__global__ __launch_bounds__(256) void gemm_a16(
    const unsigned short* __restrict__ A, const unsigned short* __restrict__ Wt,
    const float* __restrict__ bias, TY* __restrict__ Y, float scale)
{
    __shared__ unsigned short As[128 * 32];   // row-major, 32 k per row (64B)
    __shared__ unsigned short Bs[128 * 32];
    const int t = threadIdx.x;
    const int lane = t & 63, wv = t >> 6;
    const int wm = wv >> 1, wn = wv & 1;
    const int l16 = lane & 15, lq = lane >> 4;
    const int m0 = blockIdx.y * 128, n0 = blockIdx.x * 128;
    const int lrow = lane >> 2;            // 0..15 within 16-row chunk
    const int lcol = (lane & 3) * 8;       // k-elem offset (16B granules)

    f32x4 acc[4][4] = {};

    for (int k0 = 0; k0 < DIM; k0 += 32) {
        #pragma unroll
        for (int c = 0; c < 2; ++c) {
            const int ci  = wv * 2 + c;                    // chunk 0..7 (16 rows)
            const int row = ci * 16 + lrow;
            async16(A  + (size_t)(m0 + row) * DIM + k0 + lcol, &As[ci * 512]);
            async16(Wt + (size_t)(n0 + row) * DIM + k0 + lcol, &Bs[ci * 512]);
        }
        __syncthreads();   // drains vmcnt (compiler emits waitcnt before barrier)

        short8 af[4], bfr[4];
        #pragma unroll
        for (int mi = 0; mi < 4; ++mi)
            af[mi] = *(const short8*)&As[(wm * 64 + mi * 16 + l16) * 32 + lq * 8];
        #pragma unroll
        for (int nj = 0; nj < 4; ++nj)
            bfr[nj] = *(const short8*)&Bs[(wn * 64 + nj * 16 + l16) * 32 + lq * 8];
        #pragma unroll
        for (int mi = 0; mi < 4; ++mi)
            #pragma unroll
            for (int nj = 0; nj < 4; ++nj)
                acc[mi][nj] = __builtin_amdgcn_mfma_f32_16x16x32_bf16(
                    af[mi], bfr[nj], acc[mi][nj], 0, 0, 0);
        __syncthreads();
    }

    #pragma unroll
    for (int mi = 0; mi < 4; ++mi)
        #pragma unroll
        for (int nj = 0; nj < 4; ++nj) {
            const int row = m0 + wm * 64 + mi * 16 + lq * 4;
            const int col = n0 + wn * 64 + nj * 16 + l16;
            const float bb = bias[col];
            #pragma unroll
            for (int r = 0; r < 4; ++r)
                st_o(&Y[(size_t)(row + r) * DIM + col], (acc[mi][nj][r] + bb) * scale);
        }
}

// ---------- MFMA flash attention v4 ----------
// qf: pre-scaled bf16 [B,S,DIM]; kf: bf16 [B,S,DIM]; vt: bf16 [B*H][64][S].
// No online max (scores bounded; exp2-softmax), deferred row-sum reduction.
// ctx aliases qf (block reads only its own Q rows first, writes them last).
// v4 = round-0 verified staging structure (direct global->LDS between the
// two barriers; no register carry across iterations, no setprio) + the
// XCD-bijective swizzle co-locating each (b,h)'s 32 q-blocks on one XCD.
__global__ __launch_bounds__(256) void attn_mfma(
    const unsigned short* qbuf, const unsigned short* __restrict__ kbuf,
    const unsigned short* __restrict__ vtb, unsigned short* ctx)
{
    __shared__ unsigned short Qs[64][72];
    __shared__ unsigned short Ks[64][72];   // [s][d]  (B^T form for QK^T)
    __shared__ unsigned short Vs[64][72];   // [d][s]  (B^T form for PV)
    __shared__ unsigned short Ps[64][72];   // [q][s]  (A form; reused for O)

    const int t = threadIdx.x;
    const int lane = t & 63, wv = t >> 6;
    const int l16 = lane & 15, lq = lane >> 4;

    // XCD swizzle (bijective): lin = slot*8 + xcd with xcd = bh%8,
    // slot = (bh/8)*32 + q  ->  all 32 q-blocks of a (b,h) share lin%8.
    // grid = (32, 16, 4) -> lin in [0, 2048).
    const unsigned lin  = (blockIdx.z * gridDim.y + blockIdx.y) * gridDim.x + blockIdx.x;
    const unsigned xcd  = lin & 7, slot = lin >> 3;
    const unsigned bh   = ((slot >> 5) << 3) | xcd;
    const int b = (int)(bh >> 4), h = (int)(bh & 15);
    const int q0 = (int)(slot & 31) * 64;

    const size_t base  = ((size_t)b * SEQ) * DIM + h * HD;
    const size_t vbase = ((size_t)(b * NHEADS + h)) * HD * SEQ;

    {   // stage Q tile (each wave writes exactly the rows it will read)
        const int r = t >> 2, c = (t & 3) * 16;
        const unsigned short* src = qbuf + base + (size_t)(q0 + r) * DIM + c;
        *(short8*)&Qs[r][c]     = *(const short8*)src;
        *(short8*)&Qs[r][c + 8] = *(const short8*)(src + 8);
    }
    // Q fragments are wave-local rows -> no barrier needed; hoist out of loop
    const short8 aq0 = *(const short8*)&Qs[wv * 16 + l16][lq * 8];
    const short8 aq1 = *(const short8*)&Qs[wv * 16 + l16][32 + lq * 8];

    float l_part[4] = {0.f, 0.f, 0.f, 0.f};
    f32x4 O[4] = {};

    for (int s0 = 0; s0 < SEQ; s0 += 64) {
        __syncthreads();   // prev iter done reading Ks/Vs
        {   // stage K tile [s][d] — vector row loads
            const int r = t >> 2, c = (t & 3) * 16;
            const unsigned short* src = kbuf + base + (size_t)(s0 + r) * DIM + c;
            *(short8*)&Ks[r][c]     = *(const short8*)src;
            *(short8*)&Ks[r][c + 8] = *(const short8*)(src + 8);
        }
        {   // stage V^T tile [d][s] — vector row loads (pre-transposed global)
            const int d = t >> 2, c = (t & 3) * 16;
            const unsigned short* src = vtb + vbase + (size_t)d * SEQ + s0 + c;
            *(short8*)&Vs[d][c]     = *(const short8*)src;
            *(short8*)&Vs[d][c + 8] = *(const short8*)(src + 8);
        }
        __syncthreads();

        // S' = Qs Ks^T  (q pre-scaled by 0.125*log2e)
        f32x4 sa[4] = {};
        #pragma unroll
        for (int ti = 0; ti < 4; ++ti) {
            const short8 bk0 = *(const short8*)&Ks[ti * 16 + l16][lq * 8];
            const short8 bk1 = *(const short8*)&Ks[ti * 16 + l16][32 + lq * 8];
            sa[ti] = __builtin_amdgcn_mfma_f32_16x16x32_bf16(aq0, bk0, sa[ti], 0, 0, 0);
            sa[ti] = __builtin_amdgcn_mfma_f32_16x16x32_bf16(aq1, bk1, sa[ti], 0, 0, 0);
        }

        // softmax numerator: p = 2^s' ; accumulate per-lane row sums
        #pragma unroll
        for (int r = 0; r < 4; ++r) {
            const float v0 = __builtin_amdgcn_exp2f(sa[0][r]);
            const float v1 = __builtin_amdgcn_exp2f(sa[1][r]);
            const float v2 = __builtin_amdgcn_exp2f(sa[2][r]);
            const float v3 = __builtin_amdgcn_exp2f(sa[3][r]);
            l_part[r] += (v0 + v1) + (v2 + v3);
            const int prow = wv * 16 + lq * 4 + r;      // wave-local rows
            Ps[prow][l16]      = f2bf(v0);
            Ps[prow][16 + l16] = f2bf(v1);
            Ps[prow][32 + l16] = f2bf(v2);
            Ps[prow][48 + l16] = f2bf(v3);
        }
        // no barrier: each wave reads only its own Ps rows (ordered per-wave)

        // O += P @ V
        #pragma unroll
        for (int kp = 0; kp < 2; ++kp) {
            const short8 ap = *(const short8*)&Ps[wv * 16 + l16][kp * 32 + lq * 8];
            #pragma unroll
            for (int dt = 0; dt < 4; ++dt) {
                const short8 bv = *(const short8*)&Vs[dt * 16 + l16][kp * 32 + lq * 8];
                O[dt] = __builtin_amdgcn_mfma_f32_16x16x32_bf16(ap, bv, O[dt], 0, 0, 0);
            }
        }
    }

    // finish row sums (16 lanes share a row), normalize, stage, store
    #pragma unroll
    for (int r = 0; r < 4; ++r) {
        float l = l_part[r];
        #pragma unroll
        for (int msk = 1; msk < 16; msk <<= 1) l += __shfl_xor(l, msk);
        const float inv = 1.0f / l;
        const int orow = wv * 16 + lq * 4 + r;          // wave-local rows
        #pragma unroll
        for (int dt = 0; dt < 4; ++dt)
            Ps[orow][dt * 16 + l16] = f2bf(O[dt][r] * inv);
    }
    __syncthreads();
    {
        const int r = t >> 2, c = (t & 3) * 16;
        unsigned short* dst = ctx + base + (size_t)(q0 + r) * DIM + c;
        *(short8*)dst       = *(const short8*)&Ps[r][c];
        *(short8*)(dst + 8) = *(const short8*)&Ps[r][c + 8];
    }
}

extern "C" void kernel_launch(void* const* d_in, const int* in_sizes, int n_in,
                              void* d_out, int out_size, void* d_ws, size_t ws_size,
                              hipStream_t stream) {
    const float* Q  = (const float*)d_in[0];
    const float* K  = (const float*)d_in[1];
    const float* V  = (const float*)d_in[2];
    const float* Wq = (const float*)d_in[3];
    const float* bq = (const float*)d_in[4];
    const float* Wk = (const float*)d_in[5];
    const float* bk = (const float*)d_in[6];
    const float* Wv = (const float*)d_in[7];
    const float* bv = (const float*)d_in[8];
    const float* Wo = (const float*)d_in[9];
    const float* bo = (const float*)d_in[10];
    float* out = (float*)d_out;

    // ws: 4 weights (2 MB ea) + 5 x 16 MB buffers = 88 MB (<= 96 MB proven).
    // Buffer plan (lifetimes disjoint in stream order; every byte rewritten
    // every launch -> replay-safe):
    //   bufA: vb -> qf -> ctx (attn self-alias, safe)
    //   bufB: kb
    //   bufC: qb
    //   bufD: vf -> kf
    //   bufE: vt
    const size_t eW = (size_t)DIM * DIM;     // 1M elems
    const size_t eB = (size_t)M_TOT * DIM;   // 8M elems
    unsigned short* p   = (unsigned short*)d_ws;
    unsigned short* wtq = p; p += eW;
    unsigned short* wtk = p; p += eW;
    unsigned short* wtv = p; p += eW;
    unsigned short* wto = p; p += eW;
    unsigned short* bufA = p; p += eB;
    unsigned short* bufB = p; p += eB;
    unsigned short* bufC = p; p += eB;
    unsigned short* bufD = p; p += eB;
    unsigned short* bufE = p;

    wcvt4<<<dim3(32, 32, 4), 256, 0, stream>>>(Wq, Wk, Wv, Wo, wtq, wtk, wtv, wto);

    const int cvt_blocks = (int)(eB / (256 * 16));   // 2048
    cvt3<<<dim3(cvt_blocks, 3), 256, 0, stream>>>(V, Q, K, bufA, bufC, bufB);

    const dim3 gg(DIM / 128, M_TOT / 128);           // (8, 64)

    gemm_a16<unsigned short><<<gg, 256, 0, stream>>>(bufA, wtv, bv, bufD, 1.0f);   // vf
    vtrans<<<dim3(SEQ / 64, NHEADS, BATCH), 256, 0, stream>>>(bufD, bufE);         // vt
    gemm_a16<unsigned short><<<gg, 256, 0, stream>>>(bufC, wtq, bq, bufA, QSCALE); // qf
    gemm_a16<unsigned short><<<gg, 256, 0, stream>>>(bufB, wtk, bk, bufD, 1.0f);   // kf

    attn_mfma<<<dim3(SEQ / 64, NHEADS, BATCH), 256, 0, stream>>>(bufA, bufD, bufE, bufA);

    gemm_a16<float><<<gg, 256, 0, stream>>>(bufA, wto, bo, out, 1.0f);
}

// Round 3
// 408.452 us; speedup vs baseline: 1.0261x; 1.0261x over previous
//
#include <hip/hip_runtime.h>
#include <hip/hip_bf16.h>
#include <math.h>

#define DIM     1024
#define NHEADS  16
#define HD      64
#define BATCH   4
#define SEQ     2048
#define M_TOT   (BATCH * SEQ)   // 8192
#define QSCALE  0.180336880111f  // 0.125 * log2(e): softmax via exp2

using short8 = __attribute__((ext_vector_type(8))) short;   // 8 bf16 (4 VGPRs)
using bf16x4 = __attribute__((ext_vector_type(4))) short;   // 4 bf16 (2 VGPRs)
using f32x4  = __attribute__((ext_vector_type(4))) float;   // MFMA accumulator

__device__ inline unsigned short f2bf(float x) {
    __hip_bfloat16 h = __float2bfloat16(x);
    unsigned short u;
    __builtin_memcpy(&u, &h, sizeof(u));
    return u;
}
__device__ inline void st_o(float* p, float v)          { *p = v; }
__device__ inline void st_o(unsigned short* p, float v) { *p = f2bf(v); }

// async global->LDS, 16B per lane; lds ptr must be wave-uniform (lane l lands
// at lds + l*16 per HW rule); global ptr is per-lane.
__device__ inline void async16(const void* g, void* l) {
    __builtin_amdgcn_global_load_lds(
        (const __attribute__((address_space(1))) void*)g,
        (__attribute__((address_space(3))) void*)l, 16, 0, 0);
}

// ---------- fp32 -> bf16 convert, 3 tensors in one launch ----------
__global__ __launch_bounds__(256) void cvt3(
    const float* __restrict__ S0, const float* __restrict__ S1,
    const float* __restrict__ S2,
    unsigned short* __restrict__ D0, unsigned short* __restrict__ D1,
    unsigned short* __restrict__ D2)
{
    const float* src; unsigned short* dst;
    switch (blockIdx.y) {
        case 0:  src = S0; dst = D0; break;
        case 1:  src = S1; dst = D1; break;
        default: src = S2; dst = D2; break;
    }
    const size_t i = ((size_t)blockIdx.x * 256 + threadIdx.x) * 16;
    unsigned short tmp[16];
    #pragma unroll
    for (int p = 0; p < 4; ++p) {
        const float4 v = *(const float4*)(src + i + p * 4);
        tmp[p * 4 + 0] = f2bf(v.x); tmp[p * 4 + 1] = f2bf(v.y);
        tmp[p * 4 + 2] = f2bf(v.z); tmp[p * 4 + 3] = f2bf(v.w);
    }
    *(short8*)(dst + i)     = *(short8*)&tmp[0];
    *(short8*)(dst + i + 8) = *(short8*)&tmp[8];
}

// ---------- weight convert + transpose, 4 weights in one launch ----------
// Wt[n][k] = bf16(W[k][n])
__global__ __launch_bounds__(256) void wcvt4(
    const float* __restrict__ W0, const float* __restrict__ W1,
    const float* __restrict__ W2, const float* __restrict__ W3,
    unsigned short* __restrict__ T0, unsigned short* __restrict__ T1,
    unsigned short* __restrict__ T2, unsigned short* __restrict__ T3)
{
    const float* W; unsigned short* Wt;
    switch (blockIdx.z) {
        case 0:  W = W0; Wt = T0; break;
        case 1:  W = W1; Wt = T1; break;
        case 2:  W = W2; Wt = T2; break;
        default: W = W3; Wt = T3; break;
    }
    __shared__ unsigned short tile[32][33];
    const int t = threadIdx.x;
    const int tx = t & 31, ty = t >> 5;              // 32 x 8
    const int n0 = blockIdx.x * 32, k0 = blockIdx.y * 32;
    #pragma unroll
    for (int i = 0; i < 4; ++i) {
        const int kk = ty + i * 8;
        tile[kk][tx] = f2bf(W[(size_t)(k0 + kk) * DIM + n0 + tx]);
    }
    __syncthreads();
    #pragma unroll
    for (int i = 0; i < 4; ++i) {
        const int nn = ty + i * 8;
        Wt[(size_t)(n0 + nn) * DIM + k0 + tx] = tile[tx][nn];
    }
}

// ---------- V transpose: vt[(b*16+h)*64+d][s] = vf[b*S+s][h*64+d] ----------
__global__ __launch_bounds__(256) void vtrans(const unsigned short* __restrict__ vf,
                                              unsigned short* __restrict__ vt) {
    __shared__ unsigned short tile[64][72];
    const int t = threadIdx.x;
    const int b = blockIdx.z, h = blockIdx.y, s0 = blockIdx.x * 64;
    const int r = t >> 2, c = (t & 3) * 16;
    const unsigned short* src = vf + (size_t)(b * SEQ + s0 + r) * DIM + h * HD + c;
    *(short8*)&tile[r][c]     = *(const short8*)src;
    *(short8*)&tile[r][c + 8] = *(const short8*)(src + 8);
    __syncthreads();
    unsigned short tmp[16];
    #pragma unroll
    for (int j = 0; j < 16; ++j) tmp[j] = tile[c + j][r];   // r is d, c is s-off
    unsigned short* dst = vt + ((size_t)(b * NHEADS + h) * HD + r) * SEQ + s0 + c;
    *(short8*)dst       = *(short8*)&tmp[0];
    *(short8*)(dst + 8) = *(short8*)&tmp[8];
}

// ---------- MFMA GEMM body (m97 structure): Y = (A @ Wt^T + bias) * scale ----
// A: [M][1024] bf16, Wt: [N=1024][K=1024] bf16. 128x128 tile, BK=32,
// 4 waves (2x2), global_load_lds 16B staging, no LDS padding.
template <typename TY>
__device__ __forceinline__ void gemm_body(
    const unsigned short* A, const unsigned short* Wt,
    const float* bias, TY* Y, float scale,
    unsigned short* As, unsigned short* Bs)
{
    const int t = threadIdx.x;
    const int lane = t & 63, wv = t >> 6;
    const int wm = wv >> 1, wn = wv & 1;
    const int l16 = lane & 15, lq = lane >> 4;
    const int m0 = blockIdx.y * 128, n0 = blockIdx.x * 128;
    const int lrow = lane >> 2;            // 0..15 within 16-row chunk
    const int lcol = (lane & 3) * 8;       // k-elem offset (16B granules)

    f32x4 acc[4][4] = {};

    for (int k0 = 0; k0 < DIM; k0 += 32) {
        #pragma unroll
        for (int c = 0; c < 2; ++c) {
            const int ci  = wv * 2 + c;                    // chunk 0..7 (16 rows)
            const int row = ci * 16 + lrow;
            async16(A  + (size_t)(m0 + row) * DIM + k0 + lcol, &As[ci * 512]);
            async16(Wt + (size_t)(n0 + row) * DIM + k0 + lcol, &Bs[ci * 512]);
        }
        __syncthreads();   // drains vmcnt (compiler emits waitcnt before barrier)

        short8 af[4], bfr[4];
        #pragma unroll
        for (int mi = 0; mi < 4; ++mi)
            af[mi] = *(const short8*)&As[(wm * 64 + mi * 16 + l16) * 32 + lq * 8];
        #pragma unroll
        for (int nj = 0; nj < 4; ++nj)
            bfr[nj] = *(const short8*)&Bs[(wn * 64 + nj * 16 + l16) * 32 + lq * 8];
        #pragma unroll
        for (int mi = 0; mi < 4; ++mi)
            #pragma unroll
            for (int nj = 0; nj < 4; ++nj)
                acc[mi][nj] = __builtin_amdgcn_mfma_f32_16x16x32_bf16(
                    af[mi], bfr[nj], acc[mi][nj], 0, 0, 0);
        __syncthreads();
    }

    #pragma unroll
    for (int mi = 0; mi < 4; ++mi)
        #pragma unroll
        for (int nj = 0; nj < 4; ++nj) {
            const int row = m0 + wm * 64 + mi * 16 + lq * 4;
            const int col = n0 + wn * 64 + nj * 16 + l16;
            const float bb = bias[col];
            #pragma unroll
            for (int r = 0; r < 4; ++r)
                st_o(&Y[(size_t)(row + r) * DIM + col], (acc[mi][nj][r] + bb) * scale);
        }
}

template <typename TY>
__global__ __launch_bounds__(256) void gemm_a16(
    const unsigned short* __restrict__ A, const unsigned short* __restrict__ Wt,
    const float* __restrict__ bias, TY* __restrict__ Y, float scale)
{
    __shared__ unsigned short As[128 * 32];
    __shared__ unsigned short Bs[128 * 32];
    gemm_body<TY>(A, Wt, bias, Y, scale, As, Bs);
}

// Fused Q+K projection: blockIdx.z selects the problem (doubles co-resident
// blocks during the QK phase; pure pointer remap, stream-order unchanged).
__global__ __launch_bounds__(256) void gemm_qk(
    const unsigned short* Aq, const unsigned short* Wtq, const float* bq_,
    unsigned short* Yq,
    const unsigned short* Ak, const unsigned short* Wtk, const float* bk_,
    unsigned short* Yk)
{
    __shared__ unsigned short As[128 * 32];
    __shared__ unsigned short Bs[128 * 32];
    const bool k = blockIdx.z != 0;
    gemm_body<unsigned short>(k ? Ak : Aq, k ? Wtk : Wtq, k ? bk_ : bq_,
                              k ? Yk : Yq, k ? 1.0f : QSCALE, As, Bs);
}

// ---------- MFMA flash attention v5 ----------
// qf: pre-scaled bf16 [B,S,DIM]; kf: bf16 [B,S,DIM]; vt: bf16 [B*H][64][S].
// ctx aliases qf (block reads only its own Q rows first, writes them last).
// v5: swapped QK^T (mfma(K,Q) -> lane holds P[q=l16][s=lq*4+r]) feeds the
//     16x16x16 PV A-frag directly -> P never touches LDS. K/V staged by
//     double-buffered global_load_lds with XOR granule swizzle (source
//     pre-swizzled + same involution on read), ONE barrier per K/V tile;
//     no cross-barrier in-flight ops (vmcnt drained at each barrier).
__global__ __launch_bounds__(256) void attn_mfma(
    const unsigned short* qbuf, const unsigned short* __restrict__ kbuf,
    const unsigned short* __restrict__ vtb, unsigned short* ctx)
{
    __shared__ unsigned short Kls[2 * 64 * 64];   // [buf][s][d], granule-swizzled
    __shared__ unsigned short Vls[2 * 64 * 64];   // [buf][d][s], granule-swizzled
    __shared__ unsigned short Qs[64][72];

    const int t = threadIdx.x;
    const int lane = t & 63, wv = t >> 6;
    const int l16 = lane & 15, lq = lane >> 4;
    const int l7 = l16 & 7;
    const int lqh = lq >> 1, lql4 = (lq & 1) * 4;

    // XCD swizzle (bijective): all 32 q-blocks of a (b,h) share lin%8.
    const unsigned lin  = (blockIdx.z * gridDim.y + blockIdx.y) * gridDim.x + blockIdx.x;
    const unsigned xcd  = lin & 7, slot = lin >> 3;
    const unsigned bh   = ((slot >> 5) << 3) | xcd;
    const int b = (int)(bh >> 4), h = (int)(bh & 15);
    const int q0 = (int)(slot & 31) * 64;

    const size_t base  = ((size_t)b * SEQ) * DIM + h * HD;
    const size_t vbase = ((size_t)(b * NHEADS + h)) * HD * SEQ;

    // async16 staging geometry: chunk = 8 rows x 128B; lane l covers
    // row rl = l>>3, dest granule l&7. Source granule pre-swizzled by
    // XOR with (row&7) so reads use the same involution.
    const int rl   = lane >> 3;
    const int gcol = ((lane & 7) ^ rl) << 3;   // source col offset (elems)

    {   // stage Q tile (each wave writes exactly the rows it will read)
        const int r = t >> 2, c = (t & 3) * 16;
        const unsigned short* src = qbuf + base + (size_t)(q0 + r) * DIM + c;
        *(short8*)&Qs[r][c]     = *(const short8*)src;
        *(short8*)&Qs[r][c + 8] = *(const short8*)(src + 8);
    }
    // Q fragments: wave-local rows, no barrier needed; B-operand of swapped QK
    const short8 qf0 = *(const short8*)&Qs[wv * 16 + l16][lq * 8];
    const short8 qf1 = *(const short8*)&Qs[wv * 16 + l16][32 + lq * 8];

    float l_acc = 0.f;
    f32x4 O[4] = {};

    // prologue: stage tile 0 into buffer 0 (2 K-chunks + 2 V-chunks per wave)
    #pragma unroll
    for (int c = 0; c < 2; ++c) {
        const int ci = wv * 2 + c;
        async16(kbuf + base + (size_t)(ci * 8 + rl) * DIM + gcol, Kls + ci * 512);
        async16(vtb + vbase + (size_t)(ci * 8 + rl) * SEQ + gcol, Vls + ci * 512);
    }
    __syncthreads();   // vmcnt drained before barrier -> tile 0 resident

    int cur = 0;
    for (int s0 = 0; s0 < SEQ; s0 += 64) {
        const unsigned short* Kc = Kls + cur * 4096;
        const unsigned short* Vc = Vls + cur * 4096;

        // issue next-tile DMA first; latency hides under QK+softmax+PV
        if (s0 + 64 < SEQ) {
            unsigned short* Kd = Kls + (cur ^ 1) * 4096;
            unsigned short* Vd = Vls + (cur ^ 1) * 4096;
            #pragma unroll
            for (int c = 0; c < 2; ++c) {
                const int ci = wv * 2 + c;
                async16(kbuf + base + (size_t)(s0 + 64 + ci * 8 + rl) * DIM + gcol,
                        Kd + ci * 512);
                async16(vtb + vbase + (size_t)(ci * 8 + rl) * SEQ + s0 + 64 + gcol,
                        Vd + ci * 512);
            }
        }

        // S'^T = K Q^T : C[row = s = lq*4+r (per ti), col = q = l16]
        f32x4 sa[4] = {};
        #pragma unroll
        for (int ti = 0; ti < 4; ++ti) {
            const int rr = ti * 16 + l16;
            const short8 kf0 = *(const short8*)(Kc + rr * 64 + ((lq ^ l7) << 3));
            const short8 kf1 = *(const short8*)(Kc + rr * 64 + (((4 + lq) ^ l7) << 3));
            sa[ti] = __builtin_amdgcn_mfma_f32_16x16x32_bf16(kf0, qf0, sa[ti], 0, 0, 0);
            sa[ti] = __builtin_amdgcn_mfma_f32_16x16x32_bf16(kf1, qf1, sa[ti], 0, 0, 0);
        }

        // p = 2^s' in-register; this IS the 16x16x16 A-frag (k = lq*4+e)
        #pragma unroll
        for (int ti = 0; ti < 4; ++ti) {
            const float v0 = __builtin_amdgcn_exp2f(sa[ti][0]);
            const float v1 = __builtin_amdgcn_exp2f(sa[ti][1]);
            const float v2 = __builtin_amdgcn_exp2f(sa[ti][2]);
            const float v3 = __builtin_amdgcn_exp2f(sa[ti][3]);
            l_acc += (v0 + v1) + (v2 + v3);
            bf16x4 pa;
            pa[0] = (short)f2bf(v0); pa[1] = (short)f2bf(v1);
            pa[2] = (short)f2bf(v2); pa[3] = (short)f2bf(v3);
            #pragma unroll
            for (int dt = 0; dt < 4; ++dt) {
                const int vr = dt * 16 + l16;
                const bf16x4 vb = *(const bf16x4*)(
                    Vc + vr * 64 + (((2 * ti + lqh) ^ l7) << 3) + lql4);
                O[dt] = __builtin_amdgcn_mfma_f32_16x16x16bf16_1k(pa, vb, O[dt], 0, 0, 0);
            }
        }

        __syncthreads();   // drains DMA (next tile ready) + all reads of cur done
        cur ^= 1;
    }

    // row sums: lane partial covers q = wv*16+l16 over s ≡ {lq*4+0..3} (+16k);
    // reduce across the 4 lq groups -> every lane holds S(q = wv*16+l16).
    l_acc += __shfl_xor(l_acc, 16);
    l_acc += __shfl_xor(l_acc, 32);

    // O rows are q = wv*16 + lq*4 + r -> fetch that row's sum from lane lq*4+r.
    unsigned short (*Ol)[72] = (unsigned short(*)[72])Kls;   // reuse K LDS
    #pragma unroll
    for (int r = 0; r < 4; ++r) {
        const float inv = 1.0f / __shfl(l_acc, lq * 4 + r);
        const int orow = wv * 16 + lq * 4 + r;
        #pragma unroll
        for (int dt = 0; dt < 4; ++dt)
            Ol[orow][dt * 16 + l16] = f2bf(O[dt][r] * inv);
    }
    __syncthreads();
    {
        const int r = t >> 2, c = (t & 3) * 16;
        unsigned short* dst = ctx + base + (size_t)(q0 + r) * DIM + c;
        *(short8*)dst       = *(const short8*)&Ol[r][c];
        *(short8*)(dst + 8) = *(const short8*)&Ol[r][c + 8];
    }
}

extern "C" void kernel_launch(void* const* d_in, const int* in_sizes, int n_in,
                              void* d_out, int out_size, void* d_ws, size_t ws_size,
                              hipStream_t stream) {
    const float* Q  = (const float*)d_in[0];
    const float* K  = (const float*)d_in[1];
    const float* V  = (const float*)d_in[2];
    const float* Wq = (const float*)d_in[3];
    const float* bq = (const float*)d_in[4];
    const float* Wk = (const float*)d_in[5];
    const float* bk = (const float*)d_in[6];
    const float* Wv = (const float*)d_in[7];
    const float* bv = (const float*)d_in[8];
    const float* Wo = (const float*)d_in[9];
    const float* bo = (const float*)d_in[10];
    float* out = (float*)d_out;

    // ws: 4 weights (2 MB ea) + 5 x 16 MB buffers = 88 MB.
    // Buffer plan (lifetimes disjoint in stream order; every byte rewritten
    // every launch -> replay-safe):
    //   bufA: vb -> qf -> ctx (attn self-alias, safe)
    //   bufB: kb
    //   bufC: qb
    //   bufD: vf -> kf (kf written after vtrans consumed vf)
    //   bufE: vt
    const size_t eW = (size_t)DIM * DIM;     // 1M elems
    const size_t eB = (size_t)M_TOT * DIM;   // 8M elems
    unsigned short* p   = (unsigned short*)d_ws;
    unsigned short* wtq = p; p += eW;
    unsigned short* wtk = p; p += eW;
    unsigned short* wtv = p; p += eW;
    unsigned short* wto = p; p += eW;
    unsigned short* bufA = p; p += eB;
    unsigned short* bufB = p; p += eB;
    unsigned short* bufC = p; p += eB;
    unsigned short* bufD = p; p += eB;
    unsigned short* bufE = p;

    wcvt4<<<dim3(32, 32, 4), 256, 0, stream>>>(Wq, Wk, Wv, Wo, wtq, wtk, wtv, wto);

    const int cvt_blocks = (int)(eB / (256 * 16));   // 2048
    cvt3<<<dim3(cvt_blocks, 3), 256, 0, stream>>>(V, Q, K, bufA, bufC, bufB);

    const dim3 gg(DIM / 128, M_TOT / 128);           // (8, 64)

    gemm_a16<unsigned short><<<gg, 256, 0, stream>>>(bufA, wtv, bv, bufD, 1.0f); // vf
    vtrans<<<dim3(SEQ / 64, NHEADS, BATCH), 256, 0, stream>>>(bufD, bufE);       // vt
    gemm_qk<<<dim3(DIM / 128, M_TOT / 128, 2), 256, 0, stream>>>(
        bufC, wtq, bq, bufA,            // qf (overwrites vb, consumed)
        bufB, wtk, bk, bufD);           // kf (overwrites vf, consumed)

    attn_mfma<<<dim3(SEQ / 64, NHEADS, BATCH), 256, 0, stream>>>(bufA, bufD, bufE, bufA);

    gemm_a16<float><<<gg, 256, 0, stream>>>(bufA, wto, bo, out, 1.0f);
}

// Round 5
// 384.688 us; speedup vs baseline: 1.0895x; 1.0618x over previous
//
#include <hip/hip_runtime.h>
#include <hip/hip_bf16.h>
#include <math.h>

#define DIM     1024
#define NHEADS  16
#define HD      64
#define BATCH   4
#define SEQ     2048
#define M_TOT   (BATCH * SEQ)   // 8192
#define QSCALE  0.180336880111f  // 0.125 * log2(e): softmax via exp2

using short8 = __attribute__((ext_vector_type(8))) short;   // 8 bf16 (4 VGPRs)
using bf16x4 = __attribute__((ext_vector_type(4))) short;   // 4 bf16 (2 VGPRs)
using f32x4  = __attribute__((ext_vector_type(4))) float;   // MFMA accumulator

__device__ inline unsigned short f2bf(float x) {
    __hip_bfloat16 h = __float2bfloat16(x);
    unsigned short u;
    __builtin_memcpy(&u, &h, sizeof(u));
    return u;
}
__device__ inline void st_o(float* p, float v)          { *p = v; }
__device__ inline void st_o(unsigned short* p, float v) { *p = f2bf(v); }

// async global->LDS, 16B per lane; lds ptr must be wave-uniform (lane l lands
// at lds + l*16 per HW rule); global ptr is per-lane.
__device__ inline void async16(const void* g, void* l) {
    __builtin_amdgcn_global_load_lds(
        (const __attribute__((address_space(1))) void*)g,
        (__attribute__((address_space(3))) void*)l, 16, 0, 0);
}

// ---------- fp32 -> bf16 convert, 3 tensors in one launch ----------
__global__ __launch_bounds__(256) void cvt3(
    const float* __restrict__ S0, const float* __restrict__ S1,
    const float* __restrict__ S2,
    unsigned short* __restrict__ D0, unsigned short* __restrict__ D1,
    unsigned short* __restrict__ D2)
{
    const float* src; unsigned short* dst;
    switch (blockIdx.y) {
        case 0:  src = S0; dst = D0; break;
        case 1:  src = S1; dst = D1; break;
        default: src = S2; dst = D2; break;
    }
    const size_t i = ((size_t)blockIdx.x * 256 + threadIdx.x) * 16;
    unsigned short tmp[16];
    #pragma unroll
    for (int p = 0; p < 4; ++p) {
        const float4 v = *(const float4*)(src + i + p * 4);
        tmp[p * 4 + 0] = f2bf(v.x); tmp[p * 4 + 1] = f2bf(v.y);
        tmp[p * 4 + 2] = f2bf(v.z); tmp[p * 4 + 3] = f2bf(v.w);
    }
    *(short8*)(dst + i)     = *(short8*)&tmp[0];
    *(short8*)(dst + i + 8) = *(short8*)&tmp[8];
}

// ---------- weight convert + transpose, 4 weights in one launch ----------
// Wt[n][k] = bf16(W[k][n])
__global__ __launch_bounds__(256) void wcvt4(
    const float* __restrict__ W0, const float* __restrict__ W1,
    const float* __restrict__ W2, const float* __restrict__ W3,
    unsigned short* __restrict__ T0, unsigned short* __restrict__ T1,
    unsigned short* __restrict__ T2, unsigned short* __restrict__ T3)
{
    const float* W; unsigned short* Wt;
    switch (blockIdx.z) {
        case 0:  W = W0; Wt = T0; break;
        case 1:  W = W1; Wt = T1; break;
        case 2:  W = W2; Wt = T2; break;
        default: W = W3; Wt = T3; break;
    }
    __shared__ unsigned short tile[32][33];
    const int t = threadIdx.x;
    const int tx = t & 31, ty = t >> 5;              // 32 x 8
    const int n0 = blockIdx.x * 32, k0 = blockIdx.y * 32;
    #pragma unroll
    for (int i = 0; i < 4; ++i) {
        const int kk = ty + i * 8;
        tile[kk][tx] = f2bf(W[(size_t)(k0 + kk) * DIM + n0 + tx]);
    }
    __syncthreads();
    #pragma unroll
    for (int i = 0; i < 4; ++i) {
        const int nn = ty + i * 8;
        Wt[(size_t)(n0 + nn) * DIM + k0 + tx] = tile[tx][nn];
    }
}

// ---------- MFMA GEMM body (m97 structure): Y = (A @ Wt^T + bias) * scale ----
// A: [M][1024] bf16, Wt: [N=1024][K=1024] bf16. 128x128 tile, BK=32,
// 4 waves (2x2), global_load_lds 16B staging, no LDS padding.
// TRANSV: write output directly in vt layout vt[(b*16+h)*64+d][s]; the acc
// quad (4 regs) = 4 consecutive m-rows = 4 consecutive s for one (h,d).
template <typename TY, bool TRANSV>
__device__ __forceinline__ void gemm_body(
    const unsigned short* A, const unsigned short* Wt,
    const float* bias, TY* Y, float scale,
    unsigned short* As, unsigned short* Bs)
{
    const int t = threadIdx.x;
    const int lane = t & 63, wv = t >> 6;
    const int wm = wv >> 1, wn = wv & 1;
    const int l16 = lane & 15, lq = lane >> 4;
    const int m0 = blockIdx.y * 128, n0 = blockIdx.x * 128;
    const int lrow = lane >> 2;            // 0..15 within 16-row chunk
    const int lcol = (lane & 3) * 8;       // k-elem offset (16B granules)

    f32x4 acc[4][4] = {};

    for (int k0 = 0; k0 < DIM; k0 += 32) {
        #pragma unroll
        for (int c = 0; c < 2; ++c) {
            const int ci  = wv * 2 + c;                    // chunk 0..7 (16 rows)
            const int row = ci * 16 + lrow;
            async16(A  + (size_t)(m0 + row) * DIM + k0 + lcol, &As[ci * 512]);
            async16(Wt + (size_t)(n0 + row) * DIM + k0 + lcol, &Bs[ci * 512]);
        }
        __syncthreads();   // drains vmcnt (compiler emits waitcnt before barrier)

        short8 af[4], bfr[4];
        #pragma unroll
        for (int mi = 0; mi < 4; ++mi)
            af[mi] = *(const short8*)&As[(wm * 64 + mi * 16 + l16) * 32 + lq * 8];
        #pragma unroll
        for (int nj = 0; nj < 4; ++nj)
            bfr[nj] = *(const short8*)&Bs[(wn * 64 + nj * 16 + l16) * 32 + lq * 8];
        #pragma unroll
        for (int mi = 0; mi < 4; ++mi)
            #pragma unroll
            for (int nj = 0; nj < 4; ++nj)
                acc[mi][nj] = __builtin_amdgcn_mfma_f32_16x16x32_bf16(
                    af[mi], bfr[nj], acc[mi][nj], 0, 0, 0);
        __syncthreads();
    }

    #pragma unroll
    for (int mi = 0; mi < 4; ++mi)
        #pragma unroll
        for (int nj = 0; nj < 4; ++nj) {
            const int row = m0 + wm * 64 + mi * 16 + lq * 4;
            const int col = n0 + wn * 64 + nj * 16 + l16;
            const float bb = bias[col];
            if constexpr (TRANSV) {
                unsigned short o[4];
                #pragma unroll
                for (int r = 0; r < 4; ++r)
                    o[r] = f2bf((acc[mi][nj][r] + bb) * scale);
                const int bb_ = row >> 11, ss = row & (SEQ - 1);   // b, s
                unsigned short* dst = (unsigned short*)Y +
                    ((size_t)(bb_ * NHEADS + (col >> 6)) * HD + (col & 63)) * SEQ + ss;
                *(bf16x4*)dst = *(const bf16x4*)o;
            } else {
                #pragma unroll
                for (int r = 0; r < 4; ++r)
                    st_o(&Y[(size_t)(row + r) * DIM + col],
                         (acc[mi][nj][r] + bb) * scale);
            }
        }
}

template <typename TY, bool TRANSV = false>
__global__ __launch_bounds__(256) void gemm_a16(
    const unsigned short* __restrict__ A, const unsigned short* __restrict__ Wt,
    const float* __restrict__ bias, TY* __restrict__ Y, float scale)
{
    __shared__ unsigned short As[128 * 32];
    __shared__ unsigned short Bs[128 * 32];
    gemm_body<TY, TRANSV>(A, Wt, bias, Y, scale, As, Bs);
}

// Fused Q+K projection: blockIdx.z selects the problem.
__global__ __launch_bounds__(256) void gemm_qk(
    const unsigned short* Aq, const unsigned short* Wtq, const float* bq_,
    unsigned short* Yq,
    const unsigned short* Ak, const unsigned short* Wtk, const float* bk_,
    unsigned short* Yk)
{
    __shared__ unsigned short As[128 * 32];
    __shared__ unsigned short Bs[128 * 32];
    const bool k = blockIdx.z != 0;
    gemm_body<unsigned short, false>(k ? Ak : Aq, k ? Wtk : Wtq, k ? bk_ : bq_,
                                     k ? Yk : Yq, k ? 1.0f : QSCALE, As, Bs);
}

// ---------- MFMA flash attention v7 ----------
// qf: pre-scaled bf16 [B,S,DIM]; kf: bf16 [B,S,DIM]; vt: bf16 [B*H][64][S].
// ctx aliases qf (block reads only its own Q rows first, writes them last).
// v7 = round-3 verified structure (dynamic cur double-buffer, DMA K/V with
// granule XOR swizzle, swapped QK^T keeping P in registers, scalar f2bf)
// with ONE change: Q staged in unpadded [64][64] LDS via plain swizzled
// ds_writes -> total LDS 40960 B -> 4 blocks/CU (was 3).
__global__ __launch_bounds__(256) void attn_mfma(
    const unsigned short* qbuf, const unsigned short* __restrict__ kbuf,
    const unsigned short* __restrict__ vtb, unsigned short* ctx)
{
    __shared__ unsigned short Kls[2 * 64 * 64];   // [buf][s][d], granule-swizzled
    __shared__ unsigned short Vls[2 * 64 * 64];   // [buf][d][s], granule-swizzled
    __shared__ unsigned short Qls[64 * 64];       // [q][d],      granule-swizzled

    const int t = threadIdx.x;
    const int lane = t & 63, wv = t >> 6;
    const int l16 = lane & 15, lq = lane >> 4;
    const int l7 = l16 & 7;
    const int lqh = lq >> 1, lql4 = (lq & 1) * 4;

    // XCD swizzle (bijective): all 32 q-blocks of a (b,h) share lin%8.
    const unsigned lin  = (blockIdx.z * gridDim.y + blockIdx.y) * gridDim.x + blockIdx.x;
    const unsigned xcd  = lin & 7, slot = lin >> 3;
    const unsigned bh   = ((slot >> 5) << 3) | xcd;
    const int b = (int)(bh >> 4), h = (int)(bh & 15);
    const int q0 = (int)(slot & 31) * 64;

    const size_t base  = ((size_t)b * SEQ) * DIM + h * HD;
    const size_t vbase = ((size_t)(b * NHEADS + h)) * HD * SEQ;

    // async16 staging geometry: chunk = 8 rows x 128B; lane l covers
    // row rl = l>>3, dest granule l&7. Source granule pre-swizzled by
    // XOR with (row&7) so reads use the same involution.
    const int rl   = lane >> 3;
    const int gcol = ((lane & 7) ^ rl) << 3;   // source col offset (elems)

    {   // stage Q tile, swizzled plain stores (wave-local rows, no barrier)
        const int r = t >> 2, c = (t & 3) * 16;       // r in wave's own 16 rows
        const int g0 = c >> 3, rx = r & 7;
        const unsigned short* src = qbuf + base + (size_t)(q0 + r) * DIM + c;
        *(short8*)&Qls[r * 64 + ((g0 ^ rx) << 3)]       = *(const short8*)src;
        *(short8*)&Qls[r * 64 + (((g0 + 1) ^ rx) << 3)] = *(const short8*)(src + 8);
    }
    // Q fragments (same XOR involution); B-operand of swapped QK
    const int qrow = wv * 16 + l16;
    const short8 qf0 = *(const short8*)&Qls[qrow * 64 + ((lq ^ l7) << 3)];
    const short8 qf1 = *(const short8*)&Qls[qrow * 64 + (((4 + lq) ^ l7) << 3)];

    float l_acc = 0.f;
    f32x4 O[4] = {};

    // prologue: stage K/V tile 0 into buffer 0 (2 K-chunks + 2 V-chunks/wave)
    #pragma unroll
    for (int c = 0; c < 2; ++c) {
        const int ci = wv * 2 + c;
        async16(kbuf + base + (size_t)(ci * 8 + rl) * DIM + gcol, Kls + ci * 512);
        async16(vtb + vbase + (size_t)(ci * 8 + rl) * SEQ + gcol, Vls + ci * 512);
    }
    __syncthreads();   // vmcnt drained before barrier -> tile 0 resident

    int cur = 0;
    for (int s0 = 0; s0 < SEQ; s0 += 64) {
        const unsigned short* Kc = Kls + cur * 4096;
        const unsigned short* Vc = Vls + cur * 4096;

        // issue next-tile DMA first; latency hides under QK+softmax+PV
        if (s0 + 64 < SEQ) {
            unsigned short* Kd = Kls + (cur ^ 1) * 4096;
            unsigned short* Vd = Vls + (cur ^ 1) * 4096;
            #pragma unroll
            for (int c = 0; c < 2; ++c) {
                const int ci = wv * 2 + c;
                async16(kbuf + base + (size_t)(s0 + 64 + ci * 8 + rl) * DIM + gcol,
                        Kd + ci * 512);
                async16(vtb + vbase + (size_t)(ci * 8 + rl) * SEQ + s0 + 64 + gcol,
                        Vd + ci * 512);
            }
        }

        // S'^T = K Q^T : C[row = s = lq*4+r (per ti), col = q = l16]
        f32x4 sa[4] = {};
        #pragma unroll
        for (int ti = 0; ti < 4; ++ti) {
            const int rr = ti * 16 + l16;
            const short8 kf0 = *(const short8*)(Kc + rr * 64 + ((lq ^ l7) << 3));
            const short8 kf1 = *(const short8*)(Kc + rr * 64 + (((4 + lq) ^ l7) << 3));
            sa[ti] = __builtin_amdgcn_mfma_f32_16x16x32_bf16(kf0, qf0, sa[ti], 0, 0, 0);
            sa[ti] = __builtin_amdgcn_mfma_f32_16x16x32_bf16(kf1, qf1, sa[ti], 0, 0, 0);
        }

        // p = 2^s' in-register; this IS the 16x16x16 A-frag (k = lq*4+e)
        #pragma unroll
        for (int ti = 0; ti < 4; ++ti) {
            const float v0 = __builtin_amdgcn_exp2f(sa[ti][0]);
            const float v1 = __builtin_amdgcn_exp2f(sa[ti][1]);
            const float v2 = __builtin_amdgcn_exp2f(sa[ti][2]);
            const float v3 = __builtin_amdgcn_exp2f(sa[ti][3]);
            l_acc += (v0 + v1) + (v2 + v3);
            bf16x4 pa;
            pa[0] = (short)f2bf(v0); pa[1] = (short)f2bf(v1);
            pa[2] = (short)f2bf(v2); pa[3] = (short)f2bf(v3);
            #pragma unroll
            for (int dt = 0; dt < 4; ++dt) {
                const int vr = dt * 16 + l16;
                const bf16x4 vb = *(const bf16x4*)(
                    Vc + vr * 64 + (((2 * ti + lqh) ^ l7) << 3) + lql4);
                O[dt] = __builtin_amdgcn_mfma_f32_16x16x16bf16_1k(pa, vb, O[dt], 0, 0, 0);
            }
        }

        __syncthreads();   // drains DMA (next tile ready) + all reads of cur done
        cur ^= 1;
    }

    // row sums: lane partial covers q = wv*16+l16 over s ≡ {lq*4+0..3} (+16k);
    // reduce across the 4 lq groups -> every lane holds S(q = wv*16+l16).
    l_acc += __shfl_xor(l_acc, 16);
    l_acc += __shfl_xor(l_acc, 32);

    // O rows are q = wv*16 + lq*4 + r -> fetch that row's sum from lane lq*4+r.
    unsigned short (*Ol)[72] = (unsigned short(*)[72])Kls;   // reuse K LDS
    #pragma unroll
    for (int r = 0; r < 4; ++r) {
        const float inv = 1.0f / __shfl(l_acc, lq * 4 + r);
        const int orow = wv * 16 + lq * 4 + r;
        #pragma unroll
        for (int dt = 0; dt < 4; ++dt)
            Ol[orow][dt * 16 + l16] = f2bf(O[dt][r] * inv);
    }
    __syncthreads();
    {
        const int r = t >> 2, c = (t & 3) * 16;
        unsigned short* dst = ctx + base + (size_t)(q0 + r) * DIM + c;
        *(short8*)dst       = *(const short8*)&Ol[r][c];
        *(short8*)(dst + 8) = *(const short8*)&Ol[r][c + 8];
    }
}

extern "C" void kernel_launch(void* const* d_in, const int* in_sizes, int n_in,
                              void* d_out, int out_size, void* d_ws, size_t ws_size,
                              hipStream_t stream) {
    const float* Q  = (const float*)d_in[0];
    const float* K  = (const float*)d_in[1];
    const float* V  = (const float*)d_in[2];
    const float* Wq = (const float*)d_in[3];
    const float* bq = (const float*)d_in[4];
    const float* Wk = (const float*)d_in[5];
    const float* bk = (const float*)d_in[6];
    const float* Wv = (const float*)d_in[7];
    const float* bv = (const float*)d_in[8];
    const float* Wo = (const float*)d_in[9];
    const float* bo = (const float*)d_in[10];
    float* out = (float*)d_out;

    // ws: 4 weights (2 MB ea) + 5 x 16 MB buffers = 88 MB.
    // Buffer plan (lifetimes disjoint in stream order; every byte rewritten
    // every launch -> replay-safe):
    //   bufA: vb -> qf -> ctx (attn self-alias, safe)
    //   bufB: kb
    //   bufC: qb
    //   bufD: kf
    //   bufE: vt (written directly by V-GEMM transposed epilogue)
    const size_t eW = (size_t)DIM * DIM;     // 1M elems
    const size_t eB = (size_t)M_TOT * DIM;   // 8M elems
    unsigned short* p   = (unsigned short*)d_ws;
    unsigned short* wtq = p; p += eW;
    unsigned short* wtk = p; p += eW;
    unsigned short* wtv = p; p += eW;
    unsigned short* wto = p; p += eW;
    unsigned short* bufA = p; p += eB;
    unsigned short* bufB = p; p += eB;
    unsigned short* bufC = p; p += eB;
    unsigned short* bufD = p; p += eB;
    unsigned short* bufE = p;

    wcvt4<<<dim3(32, 32, 4), 256, 0, stream>>>(Wq, Wk, Wv, Wo, wtq, wtk, wtv, wto);

    const int cvt_blocks = (int)(eB / (256 * 16));   // 2048
    cvt3<<<dim3(cvt_blocks, 3), 256, 0, stream>>>(V, Q, K, bufA, bufC, bufB);

    const dim3 gg(DIM / 128, M_TOT / 128);           // (8, 64)

    gemm_a16<unsigned short, true><<<gg, 256, 0, stream>>>(
        bufA, wtv, bv, bufE, 1.0f);                  // vt directly (no vtrans)
    gemm_qk<<<dim3(DIM / 128, M_TOT / 128, 2), 256, 0, stream>>>(
        bufC, wtq, bq, bufA,            // qf (overwrites vb, consumed)
        bufB, wtk, bk, bufD);           // kf

    attn_mfma<<<dim3(SEQ / 64, NHEADS, BATCH), 256, 0, stream>>>(bufA, bufD, bufE, bufA);

    gemm_a16<float><<<gg, 256, 0, stream>>>(bufA, wto, bo, out, 1.0f);
}

// Round 6
// 383.761 us; speedup vs baseline: 1.0921x; 1.0024x over previous
//
#include <hip/hip_runtime.h>
#include <hip/hip_bf16.h>
#include <math.h>

#define DIM     1024
#define NHEADS  16
#define HD      64
#define BATCH   4
#define SEQ     2048
#define M_TOT   (BATCH * SEQ)   // 8192
#define QSCALE  0.180336880111f  // 0.125 * log2(e): softmax via exp2

using short8 = __attribute__((ext_vector_type(8))) short;   // 8 bf16 (4 VGPRs)
using bf16x4 = __attribute__((ext_vector_type(4))) short;   // 4 bf16 (2 VGPRs)
using f32x4  = __attribute__((ext_vector_type(4))) float;   // MFMA accumulator

__device__ inline unsigned short f2bf(float x) {
    __hip_bfloat16 h = __float2bfloat16(x);
    unsigned short u;
    __builtin_memcpy(&u, &h, sizeof(u));
    return u;
}
__device__ inline void st_o(float* p, float v)          { *p = v; }
__device__ inline void st_o(unsigned short* p, float v) { *p = f2bf(v); }

// async global->LDS, 16B per lane; lds ptr must be wave-uniform (lane l lands
// at lds + l*16 per HW rule); global ptr is per-lane.
__device__ inline void async16(const void* g, void* l) {
    __builtin_amdgcn_global_load_lds(
        (const __attribute__((address_space(1))) void*)g,
        (__attribute__((address_space(3))) void*)l, 16, 0, 0);
}

// ---------- fp32 -> bf16 convert, 3 tensors in one launch ----------
__global__ __launch_bounds__(256) void cvt3(
    const float* __restrict__ S0, const float* __restrict__ S1,
    const float* __restrict__ S2,
    unsigned short* __restrict__ D0, unsigned short* __restrict__ D1,
    unsigned short* __restrict__ D2)
{
    const float* src; unsigned short* dst;
    switch (blockIdx.y) {
        case 0:  src = S0; dst = D0; break;
        case 1:  src = S1; dst = D1; break;
        default: src = S2; dst = D2; break;
    }
    const size_t i = ((size_t)blockIdx.x * 256 + threadIdx.x) * 16;
    unsigned short tmp[16];
    #pragma unroll
    for (int p = 0; p < 4; ++p) {
        const float4 v = *(const float4*)(src + i + p * 4);
        tmp[p * 4 + 0] = f2bf(v.x); tmp[p * 4 + 1] = f2bf(v.y);
        tmp[p * 4 + 2] = f2bf(v.z); tmp[p * 4 + 3] = f2bf(v.w);
    }
    *(short8*)(dst + i)     = *(short8*)&tmp[0];
    *(short8*)(dst + i + 8) = *(short8*)&tmp[8];
}

// ---------- weight convert + transpose, 4 weights in one launch ----------
// Wt[n][k] = bf16(W[k][n])
__global__ __launch_bounds__(256) void wcvt4(
    const float* __restrict__ W0, const float* __restrict__ W1,
    const float* __restrict__ W2, const float* __restrict__ W3,
    unsigned short* __restrict__ T0, unsigned short* __restrict__ T1,
    unsigned short* __restrict__ T2, unsigned short* __restrict__ T3)
{
    const float* W; unsigned short* Wt;
    switch (blockIdx.z) {
        case 0:  W = W0; Wt = T0; break;
        case 1:  W = W1; Wt = T1; break;
        case 2:  W = W2; Wt = T2; break;
        default: W = W3; Wt = T3; break;
    }
    __shared__ unsigned short tile[32][33];
    const int t = threadIdx.x;
    const int tx = t & 31, ty = t >> 5;              // 32 x 8
    const int n0 = blockIdx.x * 32, k0 = blockIdx.y * 32;
    #pragma unroll
    for (int i = 0; i < 4; ++i) {
        const int kk = ty + i * 8;
        tile[kk][tx] = f2bf(W[(size_t)(k0 + kk) * DIM + n0 + tx]);
    }
    __syncthreads();
    #pragma unroll
    for (int i = 0; i < 4; ++i) {
        const int nn = ty + i * 8;
        Wt[(size_t)(n0 + nn) * DIM + k0 + tx] = tile[tx][nn];
    }
}

// ---------- MFMA GEMM body: Y = (A @ Wt^T + bias) * scale ----------
// A: [M][1024] bf16, Wt: [N=1024][K=1024] bf16. 128x128 tile, BK=32,
// 4 waves (2x2), global_load_lds 16B staging.
// v2: single-barrier double-buffered K-loop (round-3-attn pattern): issue
// next-tile DMA into buf^1, compute buf, ONE __syncthreads per step (drains
// vmcnt -> DMA resident + all reads of buf done). 33 barriers vs 64.
// TRANSV: write output directly in vt layout vt[(b*16+h)*64+d][s]; the acc
// quad (4 regs) = 4 consecutive m-rows = 4 consecutive s for one (h,d).
template <typename TY, bool TRANSV>
__device__ __forceinline__ void gemm_body(
    const unsigned short* A, const unsigned short* Wt,
    const float* bias, TY* Y, float scale,
    unsigned short* As, unsigned short* Bs)    // each [2][128*32]
{
    const int t = threadIdx.x;
    const int lane = t & 63, wv = t >> 6;
    const int wm = wv >> 1, wn = wv & 1;
    const int l16 = lane & 15, lq = lane >> 4;
    const int m0 = blockIdx.y * 128, n0 = blockIdx.x * 128;
    const int lrow = lane >> 2;            // 0..15 within 16-row chunk
    const int lcol = (lane & 3) * 8;       // k-elem offset (16B granules)

    f32x4 acc[4][4] = {};

    // prologue: stage k-tile 0 into buffer 0
    #pragma unroll
    for (int c = 0; c < 2; ++c) {
        const int ci  = wv * 2 + c;                    // chunk 0..7 (16 rows)
        const int row = ci * 16 + lrow;
        async16(A  + (size_t)(m0 + row) * DIM + lcol, &As[ci * 512]);
        async16(Wt + (size_t)(n0 + row) * DIM + lcol, &Bs[ci * 512]);
    }
    __syncthreads();   // vmcnt drained -> tile 0 resident

    int cur = 0;
    for (int k0 = 0; k0 < DIM; k0 += 32) {
        // issue next-tile DMA first; latency hides under frag reads + MFMA
        if (k0 + 32 < DIM) {
            unsigned short* Ad = As + (cur ^ 1) * 4096;
            unsigned short* Bd = Bs + (cur ^ 1) * 4096;
            #pragma unroll
            for (int c = 0; c < 2; ++c) {
                const int ci  = wv * 2 + c;
                const int row = ci * 16 + lrow;
                async16(A  + (size_t)(m0 + row) * DIM + k0 + 32 + lcol, Ad + ci * 512);
                async16(Wt + (size_t)(n0 + row) * DIM + k0 + 32 + lcol, Bd + ci * 512);
            }
        }
        const unsigned short* Ac = As + cur * 4096;
        const unsigned short* Bc = Bs + cur * 4096;

        short8 af[4], bfr[4];
        #pragma unroll
        for (int mi = 0; mi < 4; ++mi)
            af[mi] = *(const short8*)&Ac[(wm * 64 + mi * 16 + l16) * 32 + lq * 8];
        #pragma unroll
        for (int nj = 0; nj < 4; ++nj)
            bfr[nj] = *(const short8*)&Bc[(wn * 64 + nj * 16 + l16) * 32 + lq * 8];
        #pragma unroll
        for (int mi = 0; mi < 4; ++mi)
            #pragma unroll
            for (int nj = 0; nj < 4; ++nj)
                acc[mi][nj] = __builtin_amdgcn_mfma_f32_16x16x32_bf16(
                    af[mi], bfr[nj], acc[mi][nj], 0, 0, 0);

        __syncthreads();   // drains DMA (next tile ready) + all reads of cur done
        cur ^= 1;
    }

    #pragma unroll
    for (int mi = 0; mi < 4; ++mi)
        #pragma unroll
        for (int nj = 0; nj < 4; ++nj) {
            const int row = m0 + wm * 64 + mi * 16 + lq * 4;
            const int col = n0 + wn * 64 + nj * 16 + l16;
            const float bb = bias[col];
            if constexpr (TRANSV) {
                unsigned short o[4];
                #pragma unroll
                for (int r = 0; r < 4; ++r)
                    o[r] = f2bf((acc[mi][nj][r] + bb) * scale);
                const int bb_ = row >> 11, ss = row & (SEQ - 1);   // b, s
                unsigned short* dst = (unsigned short*)Y +
                    ((size_t)(bb_ * NHEADS + (col >> 6)) * HD + (col & 63)) * SEQ + ss;
                *(bf16x4*)dst = *(const bf16x4*)o;
            } else {
                #pragma unroll
                for (int r = 0; r < 4; ++r)
                    st_o(&Y[(size_t)(row + r) * DIM + col],
                         (acc[mi][nj][r] + bb) * scale);
            }
        }
}

template <typename TY, bool TRANSV = false>
__global__ __launch_bounds__(256) void gemm_a16(
    const unsigned short* __restrict__ A, const unsigned short* __restrict__ Wt,
    const float* __restrict__ bias, TY* __restrict__ Y, float scale)
{
    __shared__ unsigned short As[2 * 128 * 32];
    __shared__ unsigned short Bs[2 * 128 * 32];
    gemm_body<TY, TRANSV>(A, Wt, bias, Y, scale, As, Bs);
}

// Fused Q+K projection: blockIdx.z selects the problem.
__global__ __launch_bounds__(256) void gemm_qk(
    const unsigned short* Aq, const unsigned short* Wtq, const float* bq_,
    unsigned short* Yq,
    const unsigned short* Ak, const unsigned short* Wtk, const float* bk_,
    unsigned short* Yk)
{
    __shared__ unsigned short As[2 * 128 * 32];
    __shared__ unsigned short Bs[2 * 128 * 32];
    const bool k = blockIdx.z != 0;
    gemm_body<unsigned short, false>(k ? Ak : Aq, k ? Wtk : Wtq, k ? bk_ : bq_,
                                     k ? Yk : Yq, k ? 1.0f : QSCALE, As, Bs);
}

// ---------- MFMA flash attention v8 ----------
// qf: pre-scaled bf16 [B,S,DIM]; kf: bf16 [B,S,DIM]; vt: bf16 [B*H][64][S].
// ctx aliases qf (block reads only its own Q rows first, writes them last).
// v8 = v7 with Qls removed: Q staged through the Kls buf-0 region. Wave wv's
// Q rows occupy exactly the Kls bytes its OWN tile-0 DMA chunks overwrite
// (rows [wv*16, wv*16+16)), so there is no cross-wave hazard; an asm use of
// qf0/qf1 forces the ds_reads to complete before the DMA is issued
// (within-wave order). LDS 40960 -> 32768 B => 4-5 blocks/CU (was 3).
__global__ __launch_bounds__(256) void attn_mfma(
    const unsigned short* qbuf, const unsigned short* __restrict__ kbuf,
    const unsigned short* __restrict__ vtb, unsigned short* ctx)
{
    __shared__ unsigned short Kls[2 * 64 * 64];   // [buf][s][d], granule-swizzled
    __shared__ unsigned short Vls[2 * 64 * 64];   // [buf][d][s], granule-swizzled

    const int t = threadIdx.x;
    const int lane = t & 63, wv = t >> 6;
    const int l16 = lane & 15, lq = lane >> 4;
    const int l7 = l16 & 7;
    const int lqh = lq >> 1, lql4 = (lq & 1) * 4;

    // XCD swizzle (bijective): all 32 q-blocks of a (b,h) share lin%8.
    const unsigned lin  = (blockIdx.z * gridDim.y + blockIdx.y) * gridDim.x + blockIdx.x;
    const unsigned xcd  = lin & 7, slot = lin >> 3;
    const unsigned bh   = ((slot >> 5) << 3) | xcd;
    const int b = (int)(bh >> 4), h = (int)(bh & 15);
    const int q0 = (int)(slot & 31) * 64;

    const size_t base  = ((size_t)b * SEQ) * DIM + h * HD;
    const size_t vbase = ((size_t)(b * NHEADS + h)) * HD * SEQ;

    // async16 staging geometry: chunk = 8 rows x 128B; lane l covers
    // row rl = l>>3, dest granule l&7. Source granule pre-swizzled by
    // XOR with (row&7) so reads use the same involution.
    const int rl   = lane >> 3;
    const int gcol = ((lane & 7) ^ rl) << 3;   // source col offset (elems)

    {   // stage Q into Kls buf0, swizzled plain stores (wave-local rows)
        const int r = t >> 2, c = (t & 3) * 16;       // r in wave's own 16 rows
        const int g0 = c >> 3, rx = r & 7;
        const unsigned short* src = qbuf + base + (size_t)(q0 + r) * DIM + c;
        *(short8*)&Kls[r * 64 + ((g0 ^ rx) << 3)]       = *(const short8*)src;
        *(short8*)&Kls[r * 64 + (((g0 + 1) ^ rx) << 3)] = *(const short8*)(src + 8);
    }
    // Q fragments (same XOR involution); B-operand of swapped QK
    const int qrow = wv * 16 + l16;
    const short8 qf0 = *(const short8*)&Kls[qrow * 64 + ((lq ^ l7) << 3)];
    const short8 qf1 = *(const short8*)&Kls[qrow * 64 + (((4 + lq) ^ l7) << 3)];
    // force the frag reads to materialize before the DMA below reuses Kls
    asm volatile("" :: "v"(qf0), "v"(qf1));
    __syncthreads();

    float l_acc = 0.f;
    f32x4 O[4] = {};

    // prologue: stage K/V tile 0 into buffer 0 (2 K-chunks + 2 V-chunks/wave)
    #pragma unroll
    for (int c = 0; c < 2; ++c) {
        const int ci = wv * 2 + c;
        async16(kbuf + base + (size_t)(ci * 8 + rl) * DIM + gcol, Kls + ci * 512);
        async16(vtb + vbase + (size_t)(ci * 8 + rl) * SEQ + gcol, Vls + ci * 512);
    }
    __syncthreads();   // vmcnt drained before barrier -> tile 0 resident

    int cur = 0;
    for (int s0 = 0; s0 < SEQ; s0 += 64) {
        const unsigned short* Kc = Kls + cur * 4096;
        const unsigned short* Vc = Vls + cur * 4096;

        // issue next-tile DMA first; latency hides under QK+softmax+PV
        if (s0 + 64 < SEQ) {
            unsigned short* Kd = Kls + (cur ^ 1) * 4096;
            unsigned short* Vd = Vls + (cur ^ 1) * 4096;
            #pragma unroll
            for (int c = 0; c < 2; ++c) {
                const int ci = wv * 2 + c;
                async16(kbuf + base + (size_t)(s0 + 64 + ci * 8 + rl) * DIM + gcol,
                        Kd + ci * 512);
                async16(vtb + vbase + (size_t)(ci * 8 + rl) * SEQ + s0 + 64 + gcol,
                        Vd + ci * 512);
            }
        }

        // S'^T = K Q^T : C[row = s = lq*4+r (per ti), col = q = l16]
        f32x4 sa[4] = {};
        #pragma unroll
        for (int ti = 0; ti < 4; ++ti) {
            const int rr = ti * 16 + l16;
            const short8 kf0 = *(const short8*)(Kc + rr * 64 + ((lq ^ l7) << 3));
            const short8 kf1 = *(const short8*)(Kc + rr * 64 + (((4 + lq) ^ l7) << 3));
            sa[ti] = __builtin_amdgcn_mfma_f32_16x16x32_bf16(kf0, qf0, sa[ti], 0, 0, 0);
            sa[ti] = __builtin_amdgcn_mfma_f32_16x16x32_bf16(kf1, qf1, sa[ti], 0, 0, 0);
        }

        // p = 2^s' in-register; this IS the 16x16x16 A-frag (k = lq*4+e)
        #pragma unroll
        for (int ti = 0; ti < 4; ++ti) {
            const float v0 = __builtin_amdgcn_exp2f(sa[ti][0]);
            const float v1 = __builtin_amdgcn_exp2f(sa[ti][1]);
            const float v2 = __builtin_amdgcn_exp2f(sa[ti][2]);
            const float v3 = __builtin_amdgcn_exp2f(sa[ti][3]);
            l_acc += (v0 + v1) + (v2 + v3);
            bf16x4 pa;
            pa[0] = (short)f2bf(v0); pa[1] = (short)f2bf(v1);
            pa[2] = (short)f2bf(v2); pa[3] = (short)f2bf(v3);
            #pragma unroll
            for (int dt = 0; dt < 4; ++dt) {
                const int vr = dt * 16 + l16;
                const bf16x4 vb = *(const bf16x4*)(
                    Vc + vr * 64 + (((2 * ti + lqh) ^ l7) << 3) + lql4);
                O[dt] = __builtin_amdgcn_mfma_f32_16x16x16bf16_1k(pa, vb, O[dt], 0, 0, 0);
            }
        }

        __syncthreads();   // drains DMA (next tile ready) + all reads of cur done
        cur ^= 1;
    }

    // row sums: lane partial covers q = wv*16+l16 over s ≡ {lq*4+0..3} (+16k);
    // reduce across the 4 lq groups -> every lane holds S(q = wv*16+l16).
    l_acc += __shfl_xor(l_acc, 16);
    l_acc += __shfl_xor(l_acc, 32);

    // O rows are q = wv*16 + lq*4 + r -> fetch that row's sum from lane lq*4+r.
    unsigned short (*Ol)[72] = (unsigned short(*)[72])Kls;   // reuse K LDS
    #pragma unroll
    for (int r = 0; r < 4; ++r) {
        const float inv = 1.0f / __shfl(l_acc, lq * 4 + r);
        const int orow = wv * 16 + lq * 4 + r;
        #pragma unroll
        for (int dt = 0; dt < 4; ++dt)
            Ol[orow][dt * 16 + l16] = f2bf(O[dt][r] * inv);
    }
    __syncthreads();
    {
        const int r = t >> 2, c = (t & 3) * 16;
        unsigned short* dst = ctx + base + (size_t)(q0 + r) * DIM + c;
        *(short8*)dst       = *(const short8*)&Ol[r][c];
        *(short8*)(dst + 8) = *(const short8*)&Ol[r][c + 8];
    }
}

extern "C" void kernel_launch(void* const* d_in, const int* in_sizes, int n_in,
                              void* d_out, int out_size, void* d_ws, size_t ws_size,
                              hipStream_t stream) {
    const float* Q  = (const float*)d_in[0];
    const float* K  = (const float*)d_in[1];
    const float* V  = (const float*)d_in[2];
    const float* Wq = (const float*)d_in[3];
    const float* bq = (const float*)d_in[4];
    const float* Wk = (const float*)d_in[5];
    const float* bk = (const float*)d_in[6];
    const float* Wv = (const float*)d_in[7];
    const float* bv = (const float*)d_in[8];
    const float* Wo = (const float*)d_in[9];
    const float* bo = (const float*)d_in[10];
    float* out = (float*)d_out;

    // ws: 4 weights (2 MB ea) + 5 x 16 MB buffers = 88 MB.
    // Buffer plan (lifetimes disjoint in stream order; every byte rewritten
    // every launch -> replay-safe):
    //   bufA: vb -> qf -> ctx (attn self-alias, safe)
    //   bufB: kb
    //   bufC: qb
    //   bufD: kf
    //   bufE: vt (written directly by V-GEMM transposed epilogue)
    const size_t eW = (size_t)DIM * DIM;     // 1M elems
    const size_t eB = (size_t)M_TOT * DIM;   // 8M elems
    unsigned short* p   = (unsigned short*)d_ws;
    unsigned short* wtq = p; p += eW;
    unsigned short* wtk = p; p += eW;
    unsigned short* wtv = p; p += eW;
    unsigned short* wto = p; p += eW;
    unsigned short* bufA = p; p += eB;
    unsigned short* bufB = p; p += eB;
    unsigned short* bufC = p; p += eB;
    unsigned short* bufD = p; p += eB;
    unsigned short* bufE = p;

    wcvt4<<<dim3(32, 32, 4), 256, 0, stream>>>(Wq, Wk, Wv, Wo, wtq, wtk, wtv, wto);

    const int cvt_blocks = (int)(eB / (256 * 16));   // 2048
    cvt3<<<dim3(cvt_blocks, 3), 256, 0, stream>>>(V, Q, K, bufA, bufC, bufB);

    const dim3 gg(DIM / 128, M_TOT / 128);           // (8, 64)

    gemm_a16<unsigned short, true><<<gg, 256, 0, stream>>>(
        bufA, wtv, bv, bufE, 1.0f);                  // vt directly (no vtrans)
    gemm_qk<<<dim3(DIM / 128, M_TOT / 128, 2), 256, 0, stream>>>(
        bufC, wtq, bq, bufA,            // qf (overwrites vb, consumed)
        bufB, wtk, bk, bufD);           // kf

    attn_mfma<<<dim3(SEQ / 64, NHEADS, BATCH), 256, 0, stream>>>(bufA, bufD, bufE, bufA);

    gemm_a16<float><<<gg, 256, 0, stream>>>(bufA, wto, bo, out, 1.0f);
}

// Round 8
// 374.280 us; speedup vs baseline: 1.1198x; 1.0253x over previous
//
#include <hip/hip_runtime.h>
#include <hip/hip_bf16.h>
#include <math.h>

#define DIM     1024
#define NHEADS  16
#define HD      64
#define BATCH   4
#define SEQ     2048
#define M_TOT   (BATCH * SEQ)   // 8192
#define QSCALE  0.180336880111f  // 0.125 * log2(e): softmax via exp2

using short8 = __attribute__((ext_vector_type(8))) short;   // 8 bf16 (4 VGPRs)
using bf16x4 = __attribute__((ext_vector_type(4))) short;   // 4 bf16 (2 VGPRs)
using f32x4  = __attribute__((ext_vector_type(4))) float;   // MFMA accumulator

__device__ inline unsigned short f2bf(float x) {
    __hip_bfloat16 h = __float2bfloat16(x);
    unsigned short u;
    __builtin_memcpy(&u, &h, sizeof(u));
    return u;
}
__device__ inline void st_o(float* p, float v)          { *p = v; }
__device__ inline void st_o(unsigned short* p, float v) { *p = f2bf(v); }

// pack 2 finite-positive floats to 2 bf16 (round-half-up), 3 VALU ops
__device__ inline unsigned pk2bf(float a, float b) {
    unsigned ua, ub;
    __builtin_memcpy(&ua, &a, 4); __builtin_memcpy(&ub, &b, 4);
    ua += 0x8000u; ub += 0x8000u;
    return (ua >> 16) | (ub & 0xffff0000u);
}

// async global->LDS, 16B per lane; lds ptr must be wave-uniform (lane l lands
// at lds + l*16 per HW rule); global ptr is per-lane.
__device__ inline void async16(const void* g, void* l) {
    __builtin_amdgcn_global_load_lds(
        (const __attribute__((address_space(1))) void*)g,
        (__attribute__((address_space(3))) void*)l, 16, 0, 0);
}

// ---------- fp32 -> bf16 convert, 3 tensors in one launch ----------
__global__ __launch_bounds__(256) void cvt3(
    const float* __restrict__ S0, const float* __restrict__ S1,
    const float* __restrict__ S2,
    unsigned short* __restrict__ D0, unsigned short* __restrict__ D1,
    unsigned short* __restrict__ D2)
{
    const float* src; unsigned short* dst;
    switch (blockIdx.y) {
        case 0:  src = S0; dst = D0; break;
        case 1:  src = S1; dst = D1; break;
        default: src = S2; dst = D2; break;
    }
    const size_t i = ((size_t)blockIdx.x * 256 + threadIdx.x) * 16;
    unsigned short tmp[16];
    #pragma unroll
    for (int p = 0; p < 4; ++p) {
        const float4 v = *(const float4*)(src + i + p * 4);
        tmp[p * 4 + 0] = f2bf(v.x); tmp[p * 4 + 1] = f2bf(v.y);
        tmp[p * 4 + 2] = f2bf(v.z); tmp[p * 4 + 3] = f2bf(v.w);
    }
    *(short8*)(dst + i)     = *(short8*)&tmp[0];
    *(short8*)(dst + i + 8) = *(short8*)&tmp[8];
}

// ---------- weight convert + transpose, 4 weights in one launch ----------
// Wt[n][k] = bf16(W[k][n])
__global__ __launch_bounds__(256) void wcvt4(
    const float* __restrict__ W0, const float* __restrict__ W1,
    const float* __restrict__ W2, const float* __restrict__ W3,
    unsigned short* __restrict__ T0, unsigned short* __restrict__ T1,
    unsigned short* __restrict__ T2, unsigned short* __restrict__ T3)
{
    const float* W; unsigned short* Wt;
    switch (blockIdx.z) {
        case 0:  W = W0; Wt = T0; break;
        case 1:  W = W1; Wt = T1; break;
        case 2:  W = W2; Wt = T2; break;
        default: W = W3; Wt = T3; break;
    }
    __shared__ unsigned short tile[32][33];
    const int t = threadIdx.x;
    const int tx = t & 31, ty = t >> 5;              // 32 x 8
    const int n0 = blockIdx.x * 32, k0 = blockIdx.y * 32;
    #pragma unroll
    for (int i = 0; i < 4; ++i) {
        const int kk = ty + i * 8;
        tile[kk][tx] = f2bf(W[(size_t)(k0 + kk) * DIM + n0 + tx]);
    }
    __syncthreads();
    #pragma unroll
    for (int i = 0; i < 4; ++i) {
        const int nn = ty + i * 8;
        Wt[(size_t)(n0 + nn) * DIM + k0 + tx] = tile[tx][nn];
    }
}

// ---------- MFMA GEMM body: Y = (A @ Wt^T + bias) * scale ----------
// A: [M][1024] bf16, Wt: [N=1024][K=1024] bf16. 128x128 tile, BK=32,
// 4 waves (2x2), global_load_lds 16B staging.
// Single-barrier double-buffered K-loop: issue next-tile DMA into buf^1,
// compute buf, ONE __syncthreads per step (drains vmcnt -> DMA resident +
// all reads of buf done). TRANSV: write output directly in vt layout
// vt[(b*16+h)*64+d][s]; acc quad = 4 consecutive s for one (h,d).
template <typename TY, bool TRANSV>
__device__ __forceinline__ void gemm_body(
    const unsigned short* A, const unsigned short* Wt,
    const float* bias, TY* Y, float scale,
    unsigned short* As, unsigned short* Bs)    // each [2][128*32]
{
    const int t = threadIdx.x;
    const int lane = t & 63, wv = t >> 6;
    const int wm = wv >> 1, wn = wv & 1;
    const int l16 = lane & 15, lq = lane >> 4;
    const int m0 = blockIdx.y * 128, n0 = blockIdx.x * 128;
    const int lrow = lane >> 2;            // 0..15 within 16-row chunk
    const int lcol = (lane & 3) * 8;       // k-elem offset (16B granules)

    f32x4 acc[4][4] = {};

    // prologue: stage k-tile 0 into buffer 0
    #pragma unroll
    for (int c = 0; c < 2; ++c) {
        const int ci  = wv * 2 + c;                    // chunk 0..7 (16 rows)
        const int row = ci * 16 + lrow;
        async16(A  + (size_t)(m0 + row) * DIM + lcol, &As[ci * 512]);
        async16(Wt + (size_t)(n0 + row) * DIM + lcol, &Bs[ci * 512]);
    }
    __syncthreads();   // vmcnt drained -> tile 0 resident

    int cur = 0;
    for (int k0 = 0; k0 < DIM; k0 += 32) {
        // issue next-tile DMA first; latency hides under frag reads + MFMA
        if (k0 + 32 < DIM) {
            unsigned short* Ad = As + (cur ^ 1) * 4096;
            unsigned short* Bd = Bs + (cur ^ 1) * 4096;
            #pragma unroll
            for (int c = 0; c < 2; ++c) {
                const int ci  = wv * 2 + c;
                const int row = ci * 16 + lrow;
                async16(A  + (size_t)(m0 + row) * DIM + k0 + 32 + lcol, Ad + ci * 512);
                async16(Wt + (size_t)(n0 + row) * DIM + k0 + 32 + lcol, Bd + ci * 512);
            }
        }
        const unsigned short* Ac = As + cur * 4096;
        const unsigned short* Bc = Bs + cur * 4096;

        short8 af[4], bfr[4];
        #pragma unroll
        for (int mi = 0; mi < 4; ++mi)
            af[mi] = *(const short8*)&Ac[(wm * 64 + mi * 16 + l16) * 32 + lq * 8];
        #pragma unroll
        for (int nj = 0; nj < 4; ++nj)
            bfr[nj] = *(const short8*)&Bc[(wn * 64 + nj * 16 + l16) * 32 + lq * 8];
        #pragma unroll
        for (int mi = 0; mi < 4; ++mi)
            #pragma unroll
            for (int nj = 0; nj < 4; ++nj)
                acc[mi][nj] = __builtin_amdgcn_mfma_f32_16x16x32_bf16(
                    af[mi], bfr[nj], acc[mi][nj], 0, 0, 0);

        __syncthreads();   // drains DMA (next tile ready) + all reads of cur done
        cur ^= 1;
    }

    #pragma unroll
    for (int mi = 0; mi < 4; ++mi)
        #pragma unroll
        for (int nj = 0; nj < 4; ++nj) {
            const int row = m0 + wm * 64 + mi * 16 + lq * 4;
            const int col = n0 + wn * 64 + nj * 16 + l16;
            const float bb = bias[col];
            if constexpr (TRANSV) {
                unsigned short o[4];
                #pragma unroll
                for (int r = 0; r < 4; ++r)
                    o[r] = f2bf((acc[mi][nj][r] + bb) * scale);
                const int bb_ = row >> 11, ss = row & (SEQ - 1);   // b, s
                unsigned short* dst = (unsigned short*)Y +
                    ((size_t)(bb_ * NHEADS + (col >> 6)) * HD + (col & 63)) * SEQ + ss;
                *(bf16x4*)dst = *(const bf16x4*)o;
            } else {
                #pragma unroll
                for (int r = 0; r < 4; ++r)
                    st_o(&Y[(size_t)(row + r) * DIM + col],
                         (acc[mi][nj][r] + bb) * scale);
            }
        }
}

template <typename TY, bool TRANSV = false>
__global__ __launch_bounds__(256) void gemm_a16(
    const unsigned short* __restrict__ A, const unsigned short* __restrict__ Wt,
    const float* __restrict__ bias, TY* __restrict__ Y, float scale)
{
    __shared__ unsigned short As[2 * 128 * 32];
    __shared__ unsigned short Bs[2 * 128 * 32];
    gemm_body<TY, TRANSV>(A, Wt, bias, Y, scale, As, Bs);
}

// Fused V+Q+K projections: blockIdx.z selects the unit. 1536 blocks ->
// full-chip TLP for the whole projection phase. All reads/writes of the
// three units are disjoint buffers (qf goes to d_out scratch).
__global__ __launch_bounds__(256) void gemm_qkv(
    const unsigned short* Av, const unsigned short* Wtv, const float* bv_,
    unsigned short* Yv,
    const unsigned short* Aq, const unsigned short* Wtq, const float* bq_,
    unsigned short* Yq,
    const unsigned short* Ak, const unsigned short* Wtk, const float* bk_,
    unsigned short* Yk)
{
    __shared__ unsigned short As[2 * 128 * 32];
    __shared__ unsigned short Bs[2 * 128 * 32];
    const int z = blockIdx.z;
    if (z == 0)
        gemm_body<unsigned short, true >(Av, Wtv, bv_, Yv, 1.0f,   As, Bs);
    else if (z == 1)
        gemm_body<unsigned short, false>(Aq, Wtq, bq_, Yq, QSCALE, As, Bs);
    else
        gemm_body<unsigned short, false>(Ak, Wtk, bk_, Yk, 1.0f,   As, Bs);
}

// ---------- MFMA flash attention v9 ----------
// qf: pre-scaled bf16 [B,S,DIM] (d_out scratch); kf: bf16 [B,S,DIM];
// vt: bf16 [B*H][64][S]; ctx -> separate buffer (no aliasing).
// v9 = round-5-verified v7 structure (Qls separate, dynamic cur double
// buffer, DMA K/V with granule XOR swizzle, swapped QK^T keeping P in
// registers) + bit-pack P->bf16 (round-half-up, plain C).
__global__ __launch_bounds__(256) void attn_mfma(
    const unsigned short* __restrict__ qbuf, const unsigned short* __restrict__ kbuf,
    const unsigned short* __restrict__ vtb, unsigned short* __restrict__ ctx)
{
    __shared__ unsigned short Kls[2 * 64 * 64];   // [buf][s][d], granule-swizzled
    __shared__ unsigned short Vls[2 * 64 * 64];   // [buf][d][s], granule-swizzled
    __shared__ unsigned short Qls[64 * 64];       // [q][d],      granule-swizzled

    const int t = threadIdx.x;
    const int lane = t & 63, wv = t >> 6;
    const int l16 = lane & 15, lq = lane >> 4;
    const int l7 = l16 & 7;
    const int lqh = lq >> 1, lql4 = (lq & 1) * 4;

    // XCD swizzle (bijective): all 32 q-blocks of a (b,h) share lin%8.
    const unsigned lin  = (blockIdx.z * gridDim.y + blockIdx.y) * gridDim.x + blockIdx.x;
    const unsigned xcd  = lin & 7, slot = lin >> 3;
    const unsigned bh   = ((slot >> 5) << 3) | xcd;
    const int b = (int)(bh >> 4), h = (int)(bh & 15);
    const int q0 = (int)(slot & 31) * 64;

    const size_t base  = ((size_t)b * SEQ) * DIM + h * HD;
    const size_t vbase = ((size_t)(b * NHEADS + h)) * HD * SEQ;

    // async16 staging geometry: chunk = 8 rows x 128B; lane l covers
    // row rl = l>>3, dest granule l&7. Source granule pre-swizzled by
    // XOR with (row&7) so reads use the same involution.
    const int rl   = lane >> 3;
    const int gcol = ((lane & 7) ^ rl) << 3;   // source col offset (elems)

    {   // stage Q tile, swizzled plain stores (wave-local rows, no barrier)
        const int r = t >> 2, c = (t & 3) * 16;       // r in wave's own 16 rows
        const int g0 = c >> 3, rx = r & 7;
        const unsigned short* src = qbuf + base + (size_t)(q0 + r) * DIM + c;
        *(short8*)&Qls[r * 64 + ((g0 ^ rx) << 3)]       = *(const short8*)src;
        *(short8*)&Qls[r * 64 + (((g0 + 1) ^ rx) << 3)] = *(const short8*)(src + 8);
    }
    // Q fragments (same XOR involution); B-operand of swapped QK
    const int qrow = wv * 16 + l16;
    const short8 qf0 = *(const short8*)&Qls[qrow * 64 + ((lq ^ l7) << 3)];
    const short8 qf1 = *(const short8*)&Qls[qrow * 64 + (((4 + lq) ^ l7) << 3)];

    float l_acc = 0.f;
    f32x4 O[4] = {};

    // prologue: stage K/V tile 0 into buffer 0 (2 K-chunks + 2 V-chunks/wave)
    #pragma unroll
    for (int c = 0; c < 2; ++c) {
        const int ci = wv * 2 + c;
        async16(kbuf + base + (size_t)(ci * 8 + rl) * DIM + gcol, Kls + ci * 512);
        async16(vtb + vbase + (size_t)(ci * 8 + rl) * SEQ + gcol, Vls + ci * 512);
    }
    __syncthreads();   // vmcnt drained before barrier -> tile 0 resident

    int cur = 0;
    for (int s0 = 0; s0 < SEQ; s0 += 64) {
        const unsigned short* Kc = Kls + cur * 4096;
        const unsigned short* Vc = Vls + cur * 4096;

        // issue next-tile DMA first; latency hides under QK+softmax+PV
        if (s0 + 64 < SEQ) {
            unsigned short* Kd = Kls + (cur ^ 1) * 4096;
            unsigned short* Vd = Vls + (cur ^ 1) * 4096;
            #pragma unroll
            for (int c = 0; c < 2; ++c) {
                const int ci = wv * 2 + c;
                async16(kbuf + base + (size_t)(s0 + 64 + ci * 8 + rl) * DIM + gcol,
                        Kd + ci * 512);
                async16(vtb + vbase + (size_t)(ci * 8 + rl) * SEQ + s0 + 64 + gcol,
                        Vd + ci * 512);
            }
        }

        // S'^T = K Q^T : C[row = s = lq*4+r (per ti), col = q = l16]
        f32x4 sa[4] = {};
        #pragma unroll
        for (int ti = 0; ti < 4; ++ti) {
            const int rr = ti * 16 + l16;
            const short8 kf0 = *(const short8*)(Kc + rr * 64 + ((lq ^ l7) << 3));
            const short8 kf1 = *(const short8*)(Kc + rr * 64 + (((4 + lq) ^ l7) << 3));
            sa[ti] = __builtin_amdgcn_mfma_f32_16x16x32_bf16(kf0, qf0, sa[ti], 0, 0, 0);
            sa[ti] = __builtin_amdgcn_mfma_f32_16x16x32_bf16(kf1, qf1, sa[ti], 0, 0, 0);
        }

        // p = 2^s' in-register; this IS the 16x16x16 A-frag (k = lq*4+e)
        #pragma unroll
        for (int ti = 0; ti < 4; ++ti) {
            const float v0 = __builtin_amdgcn_exp2f(sa[ti][0]);
            const float v1 = __builtin_amdgcn_exp2f(sa[ti][1]);
            const float v2 = __builtin_amdgcn_exp2f(sa[ti][2]);
            const float v3 = __builtin_amdgcn_exp2f(sa[ti][3]);
            l_acc += (v0 + v1) + (v2 + v3);
            unsigned pw[2] = { pk2bf(v0, v1), pk2bf(v2, v3) };
            bf16x4 pa;
            __builtin_memcpy(&pa, pw, 8);
            #pragma unroll
            for (int dt = 0; dt < 4; ++dt) {
                const int vr = dt * 16 + l16;
                const bf16x4 vb = *(const bf16x4*)(
                    Vc + vr * 64 + (((2 * ti + lqh) ^ l7) << 3) + lql4);
                O[dt] = __builtin_amdgcn_mfma_f32_16x16x16bf16_1k(pa, vb, O[dt], 0, 0, 0);
            }
        }

        __syncthreads();   // drains DMA (next tile ready) + all reads of cur done
        cur ^= 1;
    }

    // row sums: lane partial covers q = wv*16+l16 over s ≡ {lq*4+0..3} (+16k);
    // reduce across the 4 lq groups -> every lane holds S(q = wv*16+l16).
    l_acc += __shfl_xor(l_acc, 16);
    l_acc += __shfl_xor(l_acc, 32);

    // O rows are q = wv*16 + lq*4 + r -> fetch that row's sum from lane lq*4+r.
    unsigned short (*Ol)[72] = (unsigned short(*)[72])Kls;   // reuse K LDS
    #pragma unroll
    for (int r = 0; r < 4; ++r) {
        const float inv = 1.0f / __shfl(l_acc, lq * 4 + r);
        const int orow = wv * 16 + lq * 4 + r;
        #pragma unroll
        for (int dt = 0; dt < 4; ++dt)
            Ol[orow][dt * 16 + l16] = f2bf(O[dt][r] * inv);
    }
    __syncthreads();
    {
        const int r = t >> 2, c = (t & 3) * 16;
        unsigned short* dst = ctx + base + (size_t)(q0 + r) * DIM + c;
        *(short8*)dst       = *(const short8*)&Ol[r][c];
        *(short8*)(dst + 8) = *(const short8*)&Ol[r][c + 8];
    }
}

extern "C" void kernel_launch(void* const* d_in, const int* in_sizes, int n_in,
                              void* d_out, int out_size, void* d_ws, size_t ws_size,
                              hipStream_t stream) {
    const float* Q  = (const float*)d_in[0];
    const float* K  = (const float*)d_in[1];
    const float* V  = (const float*)d_in[2];
    const float* Wq = (const float*)d_in[3];
    const float* bq = (const float*)d_in[4];
    const float* Wk = (const float*)d_in[5];
    const float* bk = (const float*)d_in[6];
    const float* Wv = (const float*)d_in[7];
    const float* bv = (const float*)d_in[8];
    const float* Wo = (const float*)d_in[9];
    const float* bo = (const float*)d_in[10];
    float* out = (float*)d_out;

    // ws: 4 weights (2 MB ea) + 5 x 16 MB buffers = 88 MB.
    // Buffer plan (lifetimes disjoint in stream order; every byte rewritten
    // every launch before any read -> replay-safe):
    //   bufA: vb -> ctx        bufB: kb        bufC: qb
    //   bufD: kf               bufE: vt
    //   d_out: qf scratch (bf16, first 16 MB) -> final f32 output
    const size_t eW = (size_t)DIM * DIM;     // 1M elems
    const size_t eB = (size_t)M_TOT * DIM;   // 8M elems
    unsigned short* p   = (unsigned short*)d_ws;
    unsigned short* wtq = p; p += eW;
    unsigned short* wtk = p; p += eW;
    unsigned short* wtv = p; p += eW;
    unsigned short* wto = p; p += eW;
    unsigned short* bufA = p; p += eB;
    unsigned short* bufB = p; p += eB;
    unsigned short* bufC = p; p += eB;
    unsigned short* bufD = p; p += eB;
    unsigned short* bufE = p;
    unsigned short* qfs = (unsigned short*)out;   // d_out scratch

    wcvt4<<<dim3(32, 32, 4), 256, 0, stream>>>(Wq, Wk, Wv, Wo, wtq, wtk, wtv, wto);

    const int cvt_blocks = (int)(eB / (256 * 16));   // 2048
    cvt3<<<dim3(cvt_blocks, 3), 256, 0, stream>>>(V, Q, K, bufA, bufC, bufB);

    // fused V+Q+K projections: reads {bufA,bufC,bufB,wt*}, writes {bufE,qfs,bufD}
    gemm_qkv<<<dim3(DIM / 128, M_TOT / 128, 3), 256, 0, stream>>>(
        bufA, wtv, bv, bufE,     // z=0: vt (TRANSV epilogue)
        bufC, wtq, bq, qfs,      // z=1: qf -> d_out scratch
        bufB, wtk, bk, bufD);    // z=2: kf

    attn_mfma<<<dim3(SEQ / 64, NHEADS, BATCH), 256, 0, stream>>>(qfs, bufD, bufE, bufA);

    gemm_a16<float><<<dim3(DIM / 128, M_TOT / 128), 256, 0, stream>>>(
        bufA, wto, bo, out, 1.0f);
}

// Round 9
// 356.069 us; speedup vs baseline: 1.1770x; 1.0511x over previous
//
#include <hip/hip_runtime.h>
#include <hip/hip_bf16.h>
#include <math.h>

#define DIM     1024
#define NHEADS  16
#define HD      64
#define BATCH   4
#define SEQ     2048
#define M_TOT   (BATCH * SEQ)   // 8192
#define QSCALE  0.180336880111f  // 0.125 * log2(e): softmax via exp2

using short8 = __attribute__((ext_vector_type(8))) short;   // 8 bf16 (4 VGPRs)
using bf16x4 = __attribute__((ext_vector_type(4))) short;   // 4 bf16 (2 VGPRs)
using f32x4  = __attribute__((ext_vector_type(4))) float;   // MFMA accumulator

__device__ inline unsigned short f2bf(float x) {
    __hip_bfloat16 h = __float2bfloat16(x);
    unsigned short u;
    __builtin_memcpy(&u, &h, sizeof(u));
    return u;
}
__device__ inline void st_o(float* p, float v)          { *p = v; }
__device__ inline void st_o(unsigned short* p, float v) { *p = f2bf(v); }

// pack 2 finite-positive floats to 2 bf16 (round-half-up), 3 VALU ops
__device__ inline unsigned pk2bf(float a, float b) {
    unsigned ua, ub;
    __builtin_memcpy(&ua, &a, 4); __builtin_memcpy(&ub, &b, 4);
    ua += 0x8000u; ub += 0x8000u;
    return (ua >> 16) | (ub & 0xffff0000u);
}

// async global->LDS, 16B per lane; lds ptr must be wave-uniform (lane l lands
// at lds + l*16 per HW rule); global ptr is per-lane.
__device__ inline void async16(const void* g, void* l) {
    __builtin_amdgcn_global_load_lds(
        (const __attribute__((address_space(1))) void*)g,
        (__attribute__((address_space(3))) void*)l, 16, 0, 0);
}

// ---------- fp32 -> bf16 convert, 3 tensors in one launch ----------
__global__ __launch_bounds__(256) void cvt3(
    const float* __restrict__ S0, const float* __restrict__ S1,
    const float* __restrict__ S2,
    unsigned short* __restrict__ D0, unsigned short* __restrict__ D1,
    unsigned short* __restrict__ D2)
{
    const float* src; unsigned short* dst;
    switch (blockIdx.y) {
        case 0:  src = S0; dst = D0; break;
        case 1:  src = S1; dst = D1; break;
        default: src = S2; dst = D2; break;
    }
    const size_t i = ((size_t)blockIdx.x * 256 + threadIdx.x) * 16;
    unsigned short tmp[16];
    #pragma unroll
    for (int p = 0; p < 4; ++p) {
        const float4 v = *(const float4*)(src + i + p * 4);
        tmp[p * 4 + 0] = f2bf(v.x); tmp[p * 4 + 1] = f2bf(v.y);
        tmp[p * 4 + 2] = f2bf(v.z); tmp[p * 4 + 3] = f2bf(v.w);
    }
    *(short8*)(dst + i)     = *(short8*)&tmp[0];
    *(short8*)(dst + i + 8) = *(short8*)&tmp[8];
}

// ---------- weight convert + transpose, 4 weights in one launch ----------
// Wt[n][k] = bf16(W[k][n])
__global__ __launch_bounds__(256) void wcvt4(
    const float* __restrict__ W0, const float* __restrict__ W1,
    const float* __restrict__ W2, const float* __restrict__ W3,
    unsigned short* __restrict__ T0, unsigned short* __restrict__ T1,
    unsigned short* __restrict__ T2, unsigned short* __restrict__ T3)
{
    const float* W; unsigned short* Wt;
    switch (blockIdx.z) {
        case 0:  W = W0; Wt = T0; break;
        case 1:  W = W1; Wt = T1; break;
        case 2:  W = W2; Wt = T2; break;
        default: W = W3; Wt = T3; break;
    }
    __shared__ unsigned short tile[32][33];
    const int t = threadIdx.x;
    const int tx = t & 31, ty = t >> 5;              // 32 x 8
    const int n0 = blockIdx.x * 32, k0 = blockIdx.y * 32;
    #pragma unroll
    for (int i = 0; i < 4; ++i) {
        const int kk = ty + i * 8;
        tile[kk][tx] = f2bf(W[(size_t)(k0 + kk) * DIM + n0 + tx]);
    }
    __syncthreads();
    #pragma unroll
    for (int i = 0; i < 4; ++i) {
        const int nn = ty + i * 8;
        Wt[(size_t)(n0 + nn) * DIM + k0 + tx] = tile[tx][nn];
    }
}

// ---------- MFMA GEMM body: Y = (A @ Wt^T + bias) * scale ----------
// A: [M][1024] bf16, Wt: [N=1024][K=1024] bf16. 128x128 tile, BK=32,
// 4 waves (2x2), global_load_lds 16B staging.
// Single-barrier double-buffered K-loop: issue next-tile DMA into buf^1,
// compute buf, ONE __syncthreads per step (drains vmcnt -> DMA resident +
// all reads of buf done). XCD-bijective block swizzle: grid.x is always 8
// (DIM/128) and nwg=512 (%8==0); XCD k gets a contiguous run of 64 tiles
// (8 m-tiles sharing Wt 2MB + A 2MB -> L2-resident).
// TRANSV: write output directly in vt layout vt[(b*16+h)*64+d][s]; acc
// quad = 4 consecutive m-rows = 4 consecutive s for one (h,d).
template <typename TY, bool TRANSV>
__device__ __forceinline__ void gemm_body(
    const unsigned short* A, const unsigned short* Wt,
    const float* bias, TY* Y, float scale,
    unsigned short* As, unsigned short* Bs)    // each [2][128*32]
{
    const int t = threadIdx.x;
    const int lane = t & 63, wv = t >> 6;
    const int wm = wv >> 1, wn = wv & 1;
    const int l16 = lane & 15, lq = lane >> 4;

    // XCD swizzle (bijective, per z-slice): lin%8 = XCD; slot = contiguous
    // tile index within the XCD, n-fastest (grid.x == 8 hardcoded).
    const unsigned lin = blockIdx.y * 8 + blockIdx.x;   // gridDim.x == 8
    const unsigned wg  = (lin & 7) * 64 + (lin >> 3);   // nwg=512, 64 per XCD
    const int m0 = (int)(wg >> 3) * 128, n0 = (int)(wg & 7) * 128;

    const int lrow = lane >> 2;            // 0..15 within 16-row chunk
    const int lcol = (lane & 3) * 8;       // k-elem offset (16B granules)

    f32x4 acc[4][4] = {};

    // prologue: stage k-tile 0 into buffer 0
    #pragma unroll
    for (int c = 0; c < 2; ++c) {
        const int ci  = wv * 2 + c;                    // chunk 0..7 (16 rows)
        const int row = ci * 16 + lrow;
        async16(A  + (size_t)(m0 + row) * DIM + lcol, &As[ci * 512]);
        async16(Wt + (size_t)(n0 + row) * DIM + lcol, &Bs[ci * 512]);
    }
    __syncthreads();   // vmcnt drained -> tile 0 resident

    int cur = 0;
    for (int k0 = 0; k0 < DIM; k0 += 32) {
        // issue next-tile DMA first; latency hides under frag reads + MFMA
        if (k0 + 32 < DIM) {
            unsigned short* Ad = As + (cur ^ 1) * 4096;
            unsigned short* Bd = Bs + (cur ^ 1) * 4096;
            #pragma unroll
            for (int c = 0; c < 2; ++c) {
                const int ci  = wv * 2 + c;
                const int row = ci * 16 + lrow;
                async16(A  + (size_t)(m0 + row) * DIM + k0 + 32 + lcol, Ad + ci * 512);
                async16(Wt + (size_t)(n0 + row) * DIM + k0 + 32 + lcol, Bd + ci * 512);
            }
        }
        const unsigned short* Ac = As + cur * 4096;
        const unsigned short* Bc = Bs + cur * 4096;

        short8 af[4], bfr[4];
        #pragma unroll
        for (int mi = 0; mi < 4; ++mi)
            af[mi] = *(const short8*)&Ac[(wm * 64 + mi * 16 + l16) * 32 + lq * 8];
        #pragma unroll
        for (int nj = 0; nj < 4; ++nj)
            bfr[nj] = *(const short8*)&Bc[(wn * 64 + nj * 16 + l16) * 32 + lq * 8];
        #pragma unroll
        for (int mi = 0; mi < 4; ++mi)
            #pragma unroll
            for (int nj = 0; nj < 4; ++nj)
                acc[mi][nj] = __builtin_amdgcn_mfma_f32_16x16x32_bf16(
                    af[mi], bfr[nj], acc[mi][nj], 0, 0, 0);

        __syncthreads();   // drains DMA (next tile ready) + all reads of cur done
        cur ^= 1;
    }

    #pragma unroll
    for (int mi = 0; mi < 4; ++mi)
        #pragma unroll
        for (int nj = 0; nj < 4; ++nj) {
            const int row = m0 + wm * 64 + mi * 16 + lq * 4;
            const int col = n0 + wn * 64 + nj * 16 + l16;
            const float bb = bias[col];
            if constexpr (TRANSV) {
                unsigned short o[4];
                #pragma unroll
                for (int r = 0; r < 4; ++r)
                    o[r] = f2bf((acc[mi][nj][r] + bb) * scale);
                const int bb_ = row >> 11, ss = row & (SEQ - 1);   // b, s
                unsigned short* dst = (unsigned short*)Y +
                    ((size_t)(bb_ * NHEADS + (col >> 6)) * HD + (col & 63)) * SEQ + ss;
                *(bf16x4*)dst = *(const bf16x4*)o;
            } else {
                #pragma unroll
                for (int r = 0; r < 4; ++r)
                    st_o(&Y[(size_t)(row + r) * DIM + col],
                         (acc[mi][nj][r] + bb) * scale);
            }
        }
}

template <typename TY, bool TRANSV = false>
__global__ __launch_bounds__(256) void gemm_a16(
    const unsigned short* __restrict__ A, const unsigned short* __restrict__ Wt,
    const float* __restrict__ bias, TY* __restrict__ Y, float scale)
{
    __shared__ unsigned short As[2 * 128 * 32];
    __shared__ unsigned short Bs[2 * 128 * 32];
    gemm_body<TY, TRANSV>(A, Wt, bias, Y, scale, As, Bs);
}

// Fused V+Q+K projections: blockIdx.z selects the unit. 1536 blocks ->
// full-chip TLP for the whole projection phase. All reads/writes of the
// three units are disjoint buffers (qf goes to d_out scratch).
__global__ __launch_bounds__(256) void gemm_qkv(
    const unsigned short* Av, const unsigned short* Wtv, const float* bv_,
    unsigned short* Yv,
    const unsigned short* Aq, const unsigned short* Wtq, const float* bq_,
    unsigned short* Yq,
    const unsigned short* Ak, const unsigned short* Wtk, const float* bk_,
    unsigned short* Yk)
{
    __shared__ unsigned short As[2 * 128 * 32];
    __shared__ unsigned short Bs[2 * 128 * 32];
    const int z = blockIdx.z;
    if (z == 0)
        gemm_body<unsigned short, true >(Av, Wtv, bv_, Yv, 1.0f,   As, Bs);
    else if (z == 1)
        gemm_body<unsigned short, false>(Aq, Wtq, bq_, Yq, QSCALE, As, Bs);
    else
        gemm_body<unsigned short, false>(Ak, Wtk, bk_, Yk, 1.0f,   As, Bs);
}

// ---------- MFMA flash attention v10 ----------
// qf: pre-scaled bf16 [B,S,DIM] (d_out scratch); kf: bf16 [B,S,DIM];
// vt: bf16 [B*H][64][S]; ctx -> separate buffer (no aliasing).
// v10 = v9 + s_setprio(1) around the compute phase (m191: helps when
// multiple independent blocks/CU sit at different phases; pure hint).
__global__ __launch_bounds__(256) void attn_mfma(
    const unsigned short* __restrict__ qbuf, const unsigned short* __restrict__ kbuf,
    const unsigned short* __restrict__ vtb, unsigned short* __restrict__ ctx)
{
    __shared__ unsigned short Kls[2 * 64 * 64];   // [buf][s][d], granule-swizzled
    __shared__ unsigned short Vls[2 * 64 * 64];   // [buf][d][s], granule-swizzled
    __shared__ unsigned short Qls[64 * 64];       // [q][d],      granule-swizzled

    const int t = threadIdx.x;
    const int lane = t & 63, wv = t >> 6;
    const int l16 = lane & 15, lq = lane >> 4;
    const int l7 = l16 & 7;
    const int lqh = lq >> 1, lql4 = (lq & 1) * 4;

    // XCD swizzle (bijective): all 32 q-blocks of a (b,h) share lin%8.
    const unsigned lin  = (blockIdx.z * gridDim.y + blockIdx.y) * gridDim.x + blockIdx.x;
    const unsigned xcd  = lin & 7, slot = lin >> 3;
    const unsigned bh   = ((slot >> 5) << 3) | xcd;
    const int b = (int)(bh >> 4), h = (int)(bh & 15);
    const int q0 = (int)(slot & 31) * 64;

    const size_t base  = ((size_t)b * SEQ) * DIM + h * HD;
    const size_t vbase = ((size_t)(b * NHEADS + h)) * HD * SEQ;

    // async16 staging geometry: chunk = 8 rows x 128B; lane l covers
    // row rl = l>>3, dest granule l&7. Source granule pre-swizzled by
    // XOR with (row&7) so reads use the same involution.
    const int rl   = lane >> 3;
    const int gcol = ((lane & 7) ^ rl) << 3;   // source col offset (elems)

    {   // stage Q tile, swizzled plain stores (wave-local rows, no barrier)
        const int r = t >> 2, c = (t & 3) * 16;       // r in wave's own 16 rows
        const int g0 = c >> 3, rx = r & 7;
        const unsigned short* src = qbuf + base + (size_t)(q0 + r) * DIM + c;
        *(short8*)&Qls[r * 64 + ((g0 ^ rx) << 3)]       = *(const short8*)src;
        *(short8*)&Qls[r * 64 + (((g0 + 1) ^ rx) << 3)] = *(const short8*)(src + 8);
    }
    // Q fragments (same XOR involution); B-operand of swapped QK
    const int qrow = wv * 16 + l16;
    const short8 qf0 = *(const short8*)&Qls[qrow * 64 + ((lq ^ l7) << 3)];
    const short8 qf1 = *(const short8*)&Qls[qrow * 64 + (((4 + lq) ^ l7) << 3)];

    float l_acc = 0.f;
    f32x4 O[4] = {};

    // prologue: stage K/V tile 0 into buffer 0 (2 K-chunks + 2 V-chunks/wave)
    #pragma unroll
    for (int c = 0; c < 2; ++c) {
        const int ci = wv * 2 + c;
        async16(kbuf + base + (size_t)(ci * 8 + rl) * DIM + gcol, Kls + ci * 512);
        async16(vtb + vbase + (size_t)(ci * 8 + rl) * SEQ + gcol, Vls + ci * 512);
    }
    __syncthreads();   // vmcnt drained before barrier -> tile 0 resident

    int cur = 0;
    for (int s0 = 0; s0 < SEQ; s0 += 64) {
        const unsigned short* Kc = Kls + cur * 4096;
        const unsigned short* Vc = Vls + cur * 4096;

        // issue next-tile DMA first; latency hides under QK+softmax+PV
        if (s0 + 64 < SEQ) {
            unsigned short* Kd = Kls + (cur ^ 1) * 4096;
            unsigned short* Vd = Vls + (cur ^ 1) * 4096;
            #pragma unroll
            for (int c = 0; c < 2; ++c) {
                const int ci = wv * 2 + c;
                async16(kbuf + base + (size_t)(s0 + 64 + ci * 8 + rl) * DIM + gcol,
                        Kd + ci * 512);
                async16(vtb + vbase + (size_t)(ci * 8 + rl) * SEQ + s0 + 64 + gcol,
                        Vd + ci * 512);
            }
        }

        __builtin_amdgcn_s_setprio(1);

        // S'^T = K Q^T : C[row = s = lq*4+r (per ti), col = q = l16]
        f32x4 sa[4] = {};
        #pragma unroll
        for (int ti = 0; ti < 4; ++ti) {
            const int rr = ti * 16 + l16;
            const short8 kf0 = *(const short8*)(Kc + rr * 64 + ((lq ^ l7) << 3));
            const short8 kf1 = *(const short8*)(Kc + rr * 64 + (((4 + lq) ^ l7) << 3));
            sa[ti] = __builtin_amdgcn_mfma_f32_16x16x32_bf16(kf0, qf0, sa[ti], 0, 0, 0);
            sa[ti] = __builtin_amdgcn_mfma_f32_16x16x32_bf16(kf1, qf1, sa[ti], 0, 0, 0);
        }

        // p = 2^s' in-register; this IS the 16x16x16 A-frag (k = lq*4+e)
        #pragma unroll
        for (int ti = 0; ti < 4; ++ti) {
            const float v0 = __builtin_amdgcn_exp2f(sa[ti][0]);
            const float v1 = __builtin_amdgcn_exp2f(sa[ti][1]);
            const float v2 = __builtin_amdgcn_exp2f(sa[ti][2]);
            const float v3 = __builtin_amdgcn_exp2f(sa[ti][3]);
            l_acc += (v0 + v1) + (v2 + v3);
            unsigned pw[2] = { pk2bf(v0, v1), pk2bf(v2, v3) };
            bf16x4 pa;
            __builtin_memcpy(&pa, pw, 8);
            #pragma unroll
            for (int dt = 0; dt < 4; ++dt) {
                const int vr = dt * 16 + l16;
                const bf16x4 vb = *(const bf16x4*)(
                    Vc + vr * 64 + (((2 * ti + lqh) ^ l7) << 3) + lql4);
                O[dt] = __builtin_amdgcn_mfma_f32_16x16x16bf16_1k(pa, vb, O[dt], 0, 0, 0);
            }
        }

        __builtin_amdgcn_s_setprio(0);

        __syncthreads();   // drains DMA (next tile ready) + all reads of cur done
        cur ^= 1;
    }

    // row sums: lane partial covers q = wv*16+l16 over s ≡ {lq*4+0..3} (+16k);
    // reduce across the 4 lq groups -> every lane holds S(q = wv*16+l16).
    l_acc += __shfl_xor(l_acc, 16);
    l_acc += __shfl_xor(l_acc, 32);

    // O rows are q = wv*16 + lq*4 + r -> fetch that row's sum from lane lq*4+r.
    unsigned short (*Ol)[72] = (unsigned short(*)[72])Kls;   // reuse K LDS
    #pragma unroll
    for (int r = 0; r < 4; ++r) {
        const float inv = 1.0f / __shfl(l_acc, lq * 4 + r);
        const int orow = wv * 16 + lq * 4 + r;
        #pragma unroll
        for (int dt = 0; dt < 4; ++dt)
            Ol[orow][dt * 16 + l16] = f2bf(O[dt][r] * inv);
    }
    __syncthreads();
    {
        const int r = t >> 2, c = (t & 3) * 16;
        unsigned short* dst = ctx + base + (size_t)(q0 + r) * DIM + c;
        *(short8*)dst       = *(const short8*)&Ol[r][c];
        *(short8*)(dst + 8) = *(const short8*)&Ol[r][c + 8];
    }
}

extern "C" void kernel_launch(void* const* d_in, const int* in_sizes, int n_in,
                              void* d_out, int out_size, void* d_ws, size_t ws_size,
                              hipStream_t stream) {
    const float* Q  = (const float*)d_in[0];
    const float* K  = (const float*)d_in[1];
    const float* V  = (const float*)d_in[2];
    const float* Wq = (const float*)d_in[3];
    const float* bq = (const float*)d_in[4];
    const float* Wk = (const float*)d_in[5];
    const float* bk = (const float*)d_in[6];
    const float* Wv = (const float*)d_in[7];
    const float* bv = (const float*)d_in[8];
    const float* Wo = (const float*)d_in[9];
    const float* bo = (const float*)d_in[10];
    float* out = (float*)d_out;

    // ws: 4 weights (2 MB ea) + 5 x 16 MB buffers = 88 MB.
    // Buffer plan (lifetimes disjoint in stream order; every byte rewritten
    // every launch before any read -> replay-safe):
    //   bufA: vb -> ctx        bufB: kb        bufC: qb
    //   bufD: kf               bufE: vt
    //   d_out: qf scratch (bf16, first 16 MB) -> final f32 output
    const size_t eW = (size_t)DIM * DIM;     // 1M elems
    const size_t eB = (size_t)M_TOT * DIM;   // 8M elems
    unsigned short* p   = (unsigned short*)d_ws;
    unsigned short* wtq = p; p += eW;
    unsigned short* wtk = p; p += eW;
    unsigned short* wtv = p; p += eW;
    unsigned short* wto = p; p += eW;
    unsigned short* bufA = p; p += eB;
    unsigned short* bufB = p; p += eB;
    unsigned short* bufC = p; p += eB;
    unsigned short* bufD = p; p += eB;
    unsigned short* bufE = p;
    unsigned short* qfs = (unsigned short*)out;   // d_out scratch

    wcvt4<<<dim3(32, 32, 4), 256, 0, stream>>>(Wq, Wk, Wv, Wo, wtq, wtk, wtv, wto);

    const int cvt_blocks = (int)(eB / (256 * 16));   // 2048
    cvt3<<<dim3(cvt_blocks, 3), 256, 0, stream>>>(V, Q, K, bufA, bufC, bufB);

    // fused V+Q+K projections: reads {bufA,bufC,bufB,wt*}, writes {bufE,qfs,bufD}
    gemm_qkv<<<dim3(DIM / 128, M_TOT / 128, 3), 256, 0, stream>>>(
        bufA, wtv, bv, bufE,     // z=0: vt (TRANSV epilogue)
        bufC, wtq, bq, qfs,      // z=1: qf -> d_out scratch
        bufB, wtk, bk, bufD);    // z=2: kf

    attn_mfma<<<dim3(SEQ / 64, NHEADS, BATCH), 256, 0, stream>>>(qfs, bufD, bufE, bufA);

    gemm_a16<float><<<dim3(DIM / 128, M_TOT / 128), 256, 0, stream>>>(
        bufA, wto, bo, out, 1.0f);
}